// Round 1
// baseline (9842.514 us; speedup 1.0000x reference)
//
#include <hip/hip_runtime.h>
#include <hip/hip_bf16.h>
#include <math.h>

#define BATCH 4096
#define NNEG 32768
#define HID 1024
#define PROJ 256
#define TOPK 128
#define ROWS_TOTAL 40960
#define INV_T 14.2857142857142857f  // 1/0.07

// ---------- helpers ----------
__device__ __forceinline__ unsigned fkey(float f) {
    unsigned u = __float_as_uint(f);
    return (u & 0x80000000u) ? ~u : (u | 0x80000000u);
}
__device__ __forceinline__ float fkeyinv(unsigned k) {
    unsigned u = (k & 0x80000000u) ? (k ^ 0x80000000u) : ~k;
    return __uint_as_float(u);
}

__device__ __forceinline__ float blockReduceSumF(float v, volatile float* scratch) {
    #pragma unroll
    for (int o = 32; o > 0; o >>= 1) v += __shfl_down(v, o);
    int wid = threadIdx.x >> 6, lane = threadIdx.x & 63;
    __syncthreads();
    if (lane == 0) scratch[wid] = v;
    __syncthreads();
    return scratch[0] + scratch[1] + scratch[2] + scratch[3];
}
__device__ __forceinline__ float blockReduceMaxF(float v, volatile float* scratch) {
    #pragma unroll
    for (int o = 32; o > 0; o >>= 1) v = fmaxf(v, __shfl_down(v, o));
    int wid = threadIdx.x >> 6, lane = threadIdx.x & 63;
    __syncthreads();
    if (lane == 0) scratch[wid] = v;
    __syncthreads();
    return fmaxf(fmaxf(scratch[0], scratch[1]), fmaxf(scratch[2], scratch[3]));
}
__device__ __forceinline__ int blockReduceSumI(int v, volatile int* scratch) {
    #pragma unroll
    for (int o = 32; o > 0; o >>= 1) v += __shfl_down(v, o);
    int wid = threadIdx.x >> 6, lane = threadIdx.x & 63;
    __syncthreads();
    if (lane == 0) scratch[wid] = v;
    __syncthreads();
    return scratch[0] + scratch[1] + scratch[2] + scratch[3];
}

// ---------- GEMM: C[M,N] = act(A[M,K]) @ Bw[N,K]^T + bias ----------
// APPLY_BN: A element transformed by BN (mean/rstd/gamma/beta indexed by k) then exact GELU.
template<bool APPLY_BN>
__global__ __launch_bounds__(256) void gemm_nt(
    const float* __restrict__ A, const float* __restrict__ Bw,
    const float* __restrict__ bias, float* __restrict__ C,
    int M, int N, int K,
    const float* __restrict__ gamma, const float* __restrict__ beta,
    const float* __restrict__ mean, const float* __restrict__ rstd)
{
    __shared__ float As[16][65];
    __shared__ float Bs[16][65];
    const int bm = blockIdx.y * 64;
    const int bn = blockIdx.x * 64;
    const int tid = threadIdx.x;
    const int tx = tid & 15;   // n dir
    const int ty = tid >> 4;   // m dir
    float acc[4][4] = {};

    for (int k0 = 0; k0 < K; k0 += 16) {
        #pragma unroll
        for (int i = 0; i < 4; i++) {
            int idx = tid + i * 256;
            int k = idx & 15, m = idx >> 4;
            float v = A[(size_t)(bm + m) * K + k0 + k];
            if (APPLY_BN) {
                int kc = k0 + k;
                v = gamma[kc] * (v - mean[kc]) * rstd[kc] + beta[kc];
                v = 0.5f * v * (1.0f + erff(v * 0.70710678118654752f));
            }
            As[k][m] = v;
        }
        #pragma unroll
        for (int i = 0; i < 4; i++) {
            int idx = tid + i * 256;
            int k = idx & 15, n = idx >> 4;
            Bs[k][n] = Bw[(size_t)(bn + n) * K + k0 + k];
        }
        __syncthreads();
        #pragma unroll
        for (int kk = 0; kk < 16; kk++) {
            float a[4], b[4];
            #pragma unroll
            for (int i = 0; i < 4; i++) a[i] = As[kk][ty * 4 + i];
            #pragma unroll
            for (int j = 0; j < 4; j++) b[j] = Bs[kk][tx * 4 + j];
            #pragma unroll
            for (int i = 0; i < 4; i++)
                #pragma unroll
                for (int j = 0; j < 4; j++)
                    acc[i][j] += a[i] * b[j];
        }
        __syncthreads();
    }
    #pragma unroll
    for (int i = 0; i < 4; i++) {
        int m = bm + ty * 4 + i;
        #pragma unroll
        for (int j = 0; j < 4; j++) {
            int n = bn + tx * 4 + j;
            float v = acc[i][j];
            if (bias) v += bias[n];
            C[(size_t)m * N + n] = v;
        }
    }
}

// ---------- BN stats ----------
__global__ void bn_stats(const float* __restrict__ Yseg, int rows,
                         float* __restrict__ sum, float* __restrict__ sumsq)
{
    int col = blockIdx.x * 256 + threadIdx.x;
    int r0 = blockIdx.y * 4096;
    int r1 = min(r0 + 4096, rows);
    float s = 0.f, ss = 0.f;
    for (int r = r0; r < r1; r++) {
        float v = Yseg[(size_t)r * HID + col];
        s += v; ss += v * v;
    }
    atomicAdd(&sum[col], s);
    atomicAdd(&sumsq[col], ss);
}

__global__ void bn_finalize(const float* __restrict__ sum, const float* __restrict__ sumsq,
                            float* __restrict__ mean, float* __restrict__ rstd)
{
    int seg = blockIdx.y;
    int col = blockIdx.x * 256 + threadIdx.x;
    float n = (seg == 2) ? (float)NNEG : (float)BATCH;
    float mu = sum[seg * HID + col] / n;
    float var = sumsq[seg * HID + col] / n - mu * mu;
    mean[seg * HID + col] = mu;
    rstd[seg * HID + col] = rsqrtf(var + 1e-5f);
}

// ---------- L2 normalize rows of Z [rows x 256] ----------
__global__ __launch_bounds__(256) void l2norm(float* __restrict__ Z)
{
    __shared__ float scratch[4];
    size_t r = blockIdx.x;
    float v = Z[r * PROJ + threadIdx.x];
    float t = blockReduceSumF(v * v, scratch);
    float nrm = sqrtf(t);
    float scale = 1.0f / fmaxf(nrm, 1e-12f);
    Z[r * PROJ + threadIdx.x] = v * scale;
}

// ---------- top-k (radix select) + per-row loss ----------
__global__ __launch_bounds__(256) void topk_loss(
    const float* __restrict__ sim,   // [chunk x NNEG]
    const float* __restrict__ z1, const float* __restrict__ z2,
    int rowOffset, float* __restrict__ rowloss)
{
    __shared__ int hist[256];
    __shared__ float fscratch[4];
    __shared__ int iscratch[4];
    __shared__ unsigned sel_b;
    __shared__ int sel_need;

    const int tid = threadIdx.x;
    const int grow = rowOffset + blockIdx.x;
    const float* srow = sim + (size_t)blockIdx.x * NNEG;

    // positive similarity
    float p = z1[(size_t)grow * PROJ + tid] * z2[(size_t)grow * PROJ + tid];
    float pos = blockReduceSumF(p, fscratch);

    // row max
    float lmax = -1e30f;
    for (int i = tid; i < NNEG; i += 256) lmax = fmaxf(lmax, srow[i]);
    float vmax = blockReduceMaxF(lmax, fscratch);

    // radix select: find 128th-largest key
    unsigned prefix = 0, pmask = 0;
    int need = TOPK;
    #pragma unroll
    for (int pass = 0; pass < 4; pass++) {
        int shift = 24 - 8 * pass;
        __syncthreads();
        hist[tid] = 0;
        __syncthreads();
        for (int i = tid; i < NNEG; i += 256) {
            unsigned k = fkey(srow[i]);
            if ((k & pmask) == prefix) atomicAdd(&hist[(k >> shift) & 255], 1);
        }
        __syncthreads();
        if (tid == 0) {
            int cum = 0;
            for (int b = 255; b >= 0; b--) {
                int c = hist[b];
                if (cum + c >= need) { sel_b = (unsigned)b; sel_need = need - cum; break; }
                cum += c;
            }
        }
        __syncthreads();
        prefix |= sel_b << shift;
        need = sel_need;
        pmask |= 0xFFu << shift;
    }
    unsigned tkey = prefix;
    float tval = fkeyinv(tkey);

    // logsumexp over {pos} ∪ top-128
    float m = fmaxf(vmax, pos) * INV_T;
    float s = 0.f; int cgt = 0;
    for (int i = tid; i < NNEG; i += 256) {
        float v = srow[i];
        if (fkey(v) > tkey) { s += expf(v * INV_T - m); cgt++; }
    }
    s = blockReduceSumF(s, fscratch);
    cgt = blockReduceSumI(cgt, iscratch);
    if (tid == 0) {
        float total = s + (float)(TOPK - cgt) * expf(tval * INV_T - m) + expf(pos * INV_T - m);
        float lse = m + logf(total);
        rowloss[grow] = lse - pos * INV_T;
    }
}

__global__ __launch_bounds__(256) void loss_reduce(const float* __restrict__ rowloss,
                                                   float* __restrict__ out)
{
    __shared__ float scratch[4];
    float s = 0.f;
    for (int i = threadIdx.x; i < BATCH; i += 256) s += rowloss[i];
    s = blockReduceSumF(s, scratch);
    if (threadIdx.x == 0) out[0] = s / (float)BATCH;
}

// ---------- launcher ----------
extern "C" void kernel_launch(void* const* d_in, const int* in_sizes, int n_in,
                              void* d_out, int out_size, void* d_ws, size_t ws_size,
                              hipStream_t stream)
{
    const float* h1    = (const float*)d_in[0];
    const float* h2    = (const float*)d_in[1];
    const float* hneg  = (const float*)d_in[2];
    const float* W1    = (const float*)d_in[3];
    const float* b1    = (const float*)d_in[4];
    const float* gamma = (const float*)d_in[5];
    const float* beta  = (const float*)d_in[6];
    const float* W2    = (const float*)d_in[7];
    const float* b2    = (const float*)d_in[8];
    float* out = (float*)d_out;
    float* ws  = (float*)d_ws;

    // workspace layout (floats)
    float* Y       = ws;                        // 40960*1024 = 41,943,040
    float* Z       = ws + 41943040;             // 40960*256  = 10,485,760
    float* s_sum   = ws + 52428800;             // 3*1024
    float* s_sumsq = s_sum + 3072;              // 3*1024
    float* s_mean  = s_sum + 6144;              // 3*1024
    float* s_rstd  = s_sum + 9216;              // 3*1024
    float* rowloss = ws + 52441088;             // 4096
    float* sim     = Y;                         // reuse Y after GEMM2 (1024*32768 fits)

    hipMemsetAsync(s_sum, 0, 2 * 3072 * sizeof(float), stream);

    const float* xs[3]   = { h1, h2, hneg };
    const int    rows[3] = { BATCH, BATCH, NNEG };
    const int    yoff[3] = { 0, BATCH, 2 * BATCH };

    // GEMM1: Y = X @ W1^T + b1
    for (int s = 0; s < 3; s++) {
        dim3 g(HID / 64, rows[s] / 64);
        gemm_nt<false><<<g, 256, 0, stream>>>(xs[s], W1, b1, Y + (size_t)yoff[s] * HID,
                                              rows[s], HID, HID,
                                              nullptr, nullptr, nullptr, nullptr);
    }
    // BN stats per segment
    for (int s = 0; s < 3; s++) {
        dim3 g(HID / 256, (rows[s] + 4095) / 4096);
        bn_stats<<<g, 256, 0, stream>>>(Y + (size_t)yoff[s] * HID, rows[s],
                                        s_sum + s * HID, s_sumsq + s * HID);
    }
    bn_finalize<<<dim3(HID / 256, 3), 256, 0, stream>>>(s_sum, s_sumsq, s_mean, s_rstd);

    // GEMM2: Z = GELU(BN(Y)) @ W2^T + b2
    for (int s = 0; s < 3; s++) {
        dim3 g(PROJ / 64, rows[s] / 64);
        gemm_nt<true><<<g, 256, 0, stream>>>(Y + (size_t)yoff[s] * HID, W2, b2,
                                             Z + (size_t)yoff[s] * PROJ,
                                             rows[s], PROJ, HID,
                                             gamma, beta, s_mean + s * HID, s_rstd + s * HID);
    }
    // L2 normalize all rows
    l2norm<<<ROWS_TOTAL, 256, 0, stream>>>(Z);

    // sim chunks of 1024 z1-rows, reusing Y as the sim buffer
    const float* z_neg = Z + (size_t)(2 * BATCH) * PROJ;
    const float* z2v   = Z + (size_t)BATCH * PROJ;
    for (int c = 0; c < BATCH / 1024; c++) {
        dim3 g(NNEG / 64, 1024 / 64);
        gemm_nt<false><<<g, 256, 0, stream>>>(Z + (size_t)(c * 1024) * PROJ, z_neg, nullptr,
                                              sim, 1024, NNEG, PROJ,
                                              nullptr, nullptr, nullptr, nullptr);
        topk_loss<<<1024, 256, 0, stream>>>(sim, Z, z2v, c * 1024, rowloss);
    }
    loss_reduce<<<1, 256, 0, stream>>>(rowloss, out);
}

// Round 2
// 3087.712 us; speedup vs baseline: 3.1876x; 3.1876x over previous
//
#include <hip/hip_runtime.h>
#include <hip/hip_bf16.h>
#include <math.h>

#define BATCH 4096
#define NNEG 32768
#define HID 1024
#define PROJ 256
#define TOPK 128
#define ROWS_TOTAL 40960
#define CHUNK 512
#define INV_T 14.2857142857142857f  // 1/0.07

#define BM 128
#define BN 128
#define BK 64
#define LDK 72   // padded LDS row stride (elements)

typedef __attribute__((ext_vector_type(8))) short bf16x8;
typedef __attribute__((ext_vector_type(4))) float f32x4;

// ---------- helpers ----------
__device__ __forceinline__ float b2f(unsigned short u) {
    return __uint_as_float(((unsigned)u) << 16);
}
__device__ __forceinline__ unsigned short f2b(float f) {
    unsigned u = __float_as_uint(f);
    unsigned r = (u + 0x7FFFu + ((u >> 16) & 1u)) >> 16;  // RNE
    return (unsigned short)r;
}
__device__ __forceinline__ unsigned fkey(float f) {
    unsigned u = __float_as_uint(f);
    return (u & 0x80000000u) ? ~u : (u | 0x80000000u);
}
__device__ __forceinline__ float fkeyinv(unsigned k) {
    unsigned u = (k & 0x80000000u) ? (k ^ 0x80000000u) : ~k;
    return __uint_as_float(u);
}
__device__ __forceinline__ float gelu_exact(float v) {
    return 0.5f * v * (1.0f + erff(v * 0.70710678118654752f));
}

__device__ __forceinline__ float blockReduceSumF(float v, volatile float* scratch) {
    #pragma unroll
    for (int o = 32; o > 0; o >>= 1) v += __shfl_down(v, o);
    int wid = threadIdx.x >> 6, lane = threadIdx.x & 63;
    __syncthreads();
    if (lane == 0) scratch[wid] = v;
    __syncthreads();
    return scratch[0] + scratch[1] + scratch[2] + scratch[3];
}
__device__ __forceinline__ int blockReduceSumI(int v, volatile int* scratch) {
    #pragma unroll
    for (int o = 32; o > 0; o >>= 1) v += __shfl_down(v, o);
    int wid = threadIdx.x >> 6, lane = threadIdx.x & 63;
    __syncthreads();
    if (lane == 0) scratch[wid] = v;
    __syncthreads();
    return scratch[0] + scratch[1] + scratch[2] + scratch[3];
}

// ---------- fp32 -> bf16 conversion (4 elems/thread) ----------
__global__ __launch_bounds__(256) void conv_f2b(const float* __restrict__ src,
                                                unsigned short* __restrict__ dst, int n)
{
    int i = (blockIdx.x * 256 + threadIdx.x) * 4;
    if (i + 3 < n) {
        float4 v = *(const float4*)(src + i);
        ushort4 o;
        o.x = f2b(v.x); o.y = f2b(v.y); o.z = f2b(v.z); o.w = f2b(v.w);
        *(ushort4*)(dst + i) = o;
    }
}

// ---------- MFMA GEMM: C[M,N] = act(A[M,K]) @ Bw[N,K]^T + bias ----------
// AMODE 0: A is bf16 (ushort), copied as-is.
// AMODE 1: A is fp32, converted to bf16 during staging.
// AMODE 2: A is bf16; BN (scale/shift per k) + exact GELU applied, re-converted.
template<int AMODE, bool OUT_BF16>
__global__ __launch_bounds__(256) void mfma_gemm(
    const void* __restrict__ Av, const unsigned short* __restrict__ Bw,
    const float* __restrict__ bias, void* __restrict__ Cv,
    int M, int N, int K,
    const float* __restrict__ bnscale, const float* __restrict__ bnshift)
{
    __shared__ unsigned short As[BM * LDK];
    __shared__ unsigned short Bs[BN * LDK];
    const int tid = threadIdx.x;
    const int bm = blockIdx.y * BM;
    const int bn = blockIdx.x * BN;
    const int wave = tid >> 6;
    const int lane = tid & 63;
    const int wm = (wave >> 1) * 64;
    const int wn = (wave & 1) * 64;
    const int fr = lane & 15;   // A-row / B-col / C-col
    const int fg = lane >> 4;   // k-group
    const int srow = tid >> 1;            // staging row 0..127
    const int scol = (tid & 1) * 32;      // staging col base

    f32x4 acc[4][4] = {};

    for (int k0 = 0; k0 < K; k0 += BK) {
        // ---- stage A tile [BM][BK] ----
        if (AMODE == 0) {
            const unsigned short* A = (const unsigned short*)Av;
            const uint4* src = (const uint4*)(A + (size_t)(bm + srow) * K + k0 + scol);
            uint4 v0 = src[0], v1 = src[1], v2 = src[2], v3 = src[3];
            uint4* dst = (uint4*)&As[srow * LDK + scol];
            dst[0] = v0; dst[1] = v1; dst[2] = v2; dst[3] = v3;
        } else if (AMODE == 1) {
            const float* A = (const float*)Av;
            const float* src = A + (size_t)(bm + srow) * K + k0 + scol;
            union { unsigned short us[32]; uint4 u4[4]; } tmp;
            #pragma unroll
            for (int j = 0; j < 32; j += 4) {
                float4 v = *(const float4*)(src + j);
                tmp.us[j+0] = f2b(v.x); tmp.us[j+1] = f2b(v.y);
                tmp.us[j+2] = f2b(v.z); tmp.us[j+3] = f2b(v.w);
            }
            uint4* dst = (uint4*)&As[srow * LDK + scol];
            #pragma unroll
            for (int j = 0; j < 4; j++) dst[j] = tmp.u4[j];
        } else {
            const unsigned short* A = (const unsigned short*)Av;
            const uint4* src = (const uint4*)(A + (size_t)(bm + srow) * K + k0 + scol);
            union { unsigned short us[32]; uint4 u4[4]; } raw, tmp;
            #pragma unroll
            for (int j = 0; j < 4; j++) raw.u4[j] = src[j];
            #pragma unroll
            for (int j = 0; j < 32; j++) {
                int kc = k0 + scol + j;
                float v = b2f(raw.us[j]);
                v = fmaf(v, bnscale[kc], bnshift[kc]);
                tmp.us[j] = f2b(gelu_exact(v));
            }
            uint4* dst = (uint4*)&As[srow * LDK + scol];
            #pragma unroll
            for (int j = 0; j < 4; j++) dst[j] = tmp.u4[j];
        }
        // ---- stage B tile [BN][BK] ----
        {
            const uint4* src = (const uint4*)(Bw + (size_t)(bn + srow) * K + k0 + scol);
            uint4 v0 = src[0], v1 = src[1], v2 = src[2], v3 = src[3];
            uint4* dst = (uint4*)&Bs[srow * LDK + scol];
            dst[0] = v0; dst[1] = v1; dst[2] = v2; dst[3] = v3;
        }
        __syncthreads();
        // ---- MFMA ----
        #pragma unroll
        for (int ks = 0; ks < 2; ks++) {
            bf16x8 a[4], b[4];
            #pragma unroll
            for (int mi = 0; mi < 4; mi++)
                a[mi] = *(const bf16x8*)&As[(wm + mi * 16 + fr) * LDK + ks * 32 + fg * 8];
            #pragma unroll
            for (int ni = 0; ni < 4; ni++)
                b[ni] = *(const bf16x8*)&Bs[(wn + ni * 16 + fr) * LDK + ks * 32 + fg * 8];
            #pragma unroll
            for (int mi = 0; mi < 4; mi++)
                #pragma unroll
                for (int ni = 0; ni < 4; ni++)
                    acc[mi][ni] = __builtin_amdgcn_mfma_f32_16x16x32_bf16(a[mi], b[ni], acc[mi][ni], 0, 0, 0);
        }
        __syncthreads();
    }

    // ---- epilogue: C/D layout col=lane&15, row=(lane>>4)*4+reg ----
    #pragma unroll
    for (int mi = 0; mi < 4; mi++) {
        #pragma unroll
        for (int ni = 0; ni < 4; ni++) {
            int col = bn + wn + ni * 16 + fr;
            int row0 = bm + wm + mi * 16 + fg * 4;
            float bv = bias ? bias[col] : 0.0f;
            #pragma unroll
            for (int r = 0; r < 4; r++) {
                float v = acc[mi][ni][r] + bv;
                if (OUT_BF16) {
                    ((unsigned short*)Cv)[(size_t)(row0 + r) * N + col] = f2b(v);
                } else {
                    ((float*)Cv)[(size_t)(row0 + r) * N + col] = v;
                }
            }
        }
    }
}

// ---------- BN stats over bf16 Y: block = 128 rows x 1024 cols ----------
__global__ __launch_bounds__(256) void bn_stats(const unsigned short* __restrict__ Yb, int rows,
                                                float* __restrict__ sum, float* __restrict__ sumsq)
{
    int cg = (threadIdx.x & 127) * 8;
    int r = blockIdx.x * 128 + (threadIdx.x >> 7);
    float s[8] = {}, ss[8] = {};
    for (int i = 0; i < 64; i++, r += 2) {
        uint4 v = *(const uint4*)&Yb[(size_t)r * HID + cg];
        const unsigned short* u = (const unsigned short*)&v;
        #pragma unroll
        for (int j = 0; j < 8; j++) {
            float f = b2f(u[j]);
            s[j] += f; ss[j] += f * f;
        }
    }
    #pragma unroll
    for (int j = 0; j < 8; j++) {
        atomicAdd(&sum[cg + j], s[j]);
        atomicAdd(&sumsq[cg + j], ss[j]);
    }
}

__global__ void bn_finalize(const float* __restrict__ sum, const float* __restrict__ sumsq,
                            const float* __restrict__ gamma, const float* __restrict__ beta,
                            float* __restrict__ scale, float* __restrict__ shift)
{
    int seg = blockIdx.y;
    int col = blockIdx.x * 256 + threadIdx.x;
    float n = (seg == 2) ? (float)NNEG : (float)BATCH;
    float mu = sum[seg * HID + col] / n;
    float var = sumsq[seg * HID + col] / n - mu * mu;
    float sc = gamma[col] * rsqrtf(var + 1e-5f);
    scale[seg * HID + col] = sc;
    shift[seg * HID + col] = beta[col] - mu * sc;
}

// ---------- L2 normalize rows of Z [rows x 256]; write fp32 + bf16 ----------
__global__ __launch_bounds__(256) void l2norm(float* __restrict__ Z, unsigned short* __restrict__ Zb)
{
    __shared__ float scratch[4];
    size_t r = blockIdx.x;
    float v = Z[r * PROJ + threadIdx.x];
    float t = blockReduceSumF(v * v, scratch);
    float scale = 1.0f / fmaxf(sqrtf(t), 1e-12f);
    float o = v * scale;
    Z[r * PROJ + threadIdx.x] = o;
    Zb[r * PROJ + threadIdx.x] = f2b(o);
}

// ---------- top-k (radix select) + per-row loss ----------
__global__ __launch_bounds__(256) void topk_loss(
    const float* __restrict__ sim,   // [CHUNK x NNEG]
    const float* __restrict__ z1, const float* __restrict__ z2,
    int rowOffset, float* __restrict__ rowloss)
{
    __shared__ int hist[256];
    __shared__ float fscratch[4];
    __shared__ int iscratch[4];
    __shared__ unsigned sel_b;
    __shared__ int sel_need;

    const int tid = threadIdx.x;
    const int grow = rowOffset + blockIdx.x;
    const float* srow = sim + (size_t)blockIdx.x * NNEG;

    // positive similarity (fp32 z)
    float p = z1[(size_t)grow * PROJ + tid] * z2[(size_t)grow * PROJ + tid];
    float pos = blockReduceSumF(p, fscratch);

    // radix select: find 128th-largest key (4 x 8-bit passes)
    unsigned prefix = 0, pmask = 0;
    int need = TOPK;
    #pragma unroll
    for (int pass = 0; pass < 4; pass++) {
        int shift = 24 - 8 * pass;
        __syncthreads();
        hist[tid] = 0;
        __syncthreads();
        for (int i = tid; i < NNEG; i += 256) {
            unsigned k = fkey(srow[i]);
            if ((k & pmask) == prefix) atomicAdd(&hist[(k >> shift) & 255], 1);
        }
        __syncthreads();
        if (tid == 0) {
            int cum = 0;
            for (int b = 255; b >= 0; b--) {
                int c = hist[b];
                if (cum + c >= need) { sel_b = (unsigned)b; sel_need = need - cum; break; }
                cum += c;
            }
        }
        __syncthreads();
        prefix |= sel_b << shift;
        need = sel_need;
        pmask |= 0xFFu << shift;
    }
    unsigned tkey = prefix;
    float tval = fkeyinv(tkey);

    // logsumexp over {pos} U top-128; sims <= ~1 so m = 1*INV_T is a safe shift
    const float m = INV_T;
    float s = 0.f; int cgt = 0;
    for (int i = tid; i < NNEG; i += 256) {
        float v = srow[i];
        if (fkey(v) > tkey) { s += __expf(v * INV_T - m); cgt++; }
    }
    s = blockReduceSumF(s, fscratch);
    cgt = blockReduceSumI(cgt, iscratch);
    if (tid == 0) {
        float total = s + (float)(TOPK - cgt) * __expf(tval * INV_T - m) + __expf(pos * INV_T - m);
        float lse = m + logf(total);
        rowloss[grow] = lse - pos * INV_T;
    }
}

__global__ __launch_bounds__(256) void loss_reduce(const float* __restrict__ rowloss,
                                                   float* __restrict__ out)
{
    __shared__ float scratch[4];
    float s = 0.f;
    for (int i = threadIdx.x; i < BATCH; i += 256) s += rowloss[i];
    s = blockReduceSumF(s, scratch);
    if (threadIdx.x == 0) out[0] = s / (float)BATCH;
}

// ---------- launcher ----------
extern "C" void kernel_launch(void* const* d_in, const int* in_sizes, int n_in,
                              void* d_out, int out_size, void* d_ws, size_t ws_size,
                              hipStream_t stream)
{
    const float* h1    = (const float*)d_in[0];
    const float* h2    = (const float*)d_in[1];
    const float* hneg  = (const float*)d_in[2];
    const float* W1    = (const float*)d_in[3];
    const float* b1    = (const float*)d_in[4];
    const float* gamma = (const float*)d_in[5];
    const float* beta  = (const float*)d_in[6];
    const float* W2    = (const float*)d_in[7];
    const float* b2    = (const float*)d_in[8];
    float* out = (float*)d_out;
    float* ws  = (float*)d_ws;

    // workspace layout (float offsets)
    unsigned short* Yb  = (unsigned short*)ws;                    // 40960x1024 bf16 = 20,971,520 f
    float*          Z   = ws + 20971520;                          // 40960x256 f32   = 10,485,760 f
    unsigned short* Zb  = (unsigned short*)(ws + 31457280);       // 40960x256 bf16  =  5,242,880 f
    unsigned short* W1b = (unsigned short*)(ws + 36700160);       // 1Mx bf16        =    524,288 f
    unsigned short* W2b = (unsigned short*)(ws + 37224448);       // 256K bf16       =    131,072 f
    float* s_sum   = ws + 37355520;                               // 3*1024
    float* s_sumsq = s_sum + 3072;
    float* s_scale = s_sum + 6144;
    float* s_shift = s_sum + 9216;
    float* rowloss = ws + 37367808;                               // 4096
    float* sim     = ws;                                          // overlay Yb (dead after GEMM2)

    hipMemsetAsync(s_sum, 0, 2 * 3072 * sizeof(float), stream);

    // weights -> bf16
    conv_f2b<<<1024, 256, 0, stream>>>(W1, W1b, HID * HID);
    conv_f2b<<<256, 256, 0, stream>>>(W2, W2b, PROJ * HID);

    const float* xs[3]   = { h1, h2, hneg };
    const int    rows[3] = { BATCH, BATCH, NNEG };
    const int    yoff[3] = { 0, BATCH, 2 * BATCH };

    // GEMM1: Yb = bf16(X) @ W1b^T + b1  (fp32 A staged with conversion)
    for (int s = 0; s < 3; s++) {
        dim3 g(HID / BN, rows[s] / BM);
        mfma_gemm<1, true><<<g, 256, 0, stream>>>(xs[s], W1b, b1,
                                                  Yb + (size_t)yoff[s] * HID,
                                                  rows[s], HID, HID, nullptr, nullptr);
    }
    // BN stats + finalize (scale/shift form)
    for (int s = 0; s < 3; s++) {
        bn_stats<<<rows[s] / 128, 256, 0, stream>>>(Yb + (size_t)yoff[s] * HID, rows[s],
                                                    s_sum + s * HID, s_sumsq + s * HID);
    }
    bn_finalize<<<dim3(HID / 256, 3), 256, 0, stream>>>(s_sum, s_sumsq, gamma, beta, s_scale, s_shift);

    // GEMM2: Z = GELU(BN(Yb)) @ W2b^T + b2
    for (int s = 0; s < 3; s++) {
        dim3 g(PROJ / BN, rows[s] / BM);
        mfma_gemm<2, false><<<g, 256, 0, stream>>>(Yb + (size_t)yoff[s] * HID, W2b, b2,
                                                   Z + (size_t)yoff[s] * PROJ,
                                                   rows[s], PROJ, HID,
                                                   s_scale + s * HID, s_shift + s * HID);
    }
    // L2 normalize (fp32 + bf16 outputs)
    l2norm<<<ROWS_TOTAL, 256, 0, stream>>>(Z, Zb);

    // sim chunks: sim = z1_chunk @ z_neg^T  (bf16 MFMA), then fused topk+loss
    const unsigned short* znegb = Zb + (size_t)(2 * BATCH) * PROJ;
    const float* z2v = Z + (size_t)BATCH * PROJ;
    for (int c = 0; c < BATCH / CHUNK; c++) {
        dim3 g(NNEG / BN, CHUNK / BM);
        mfma_gemm<0, false><<<g, 256, 0, stream>>>(Zb + (size_t)(c * CHUNK) * PROJ, znegb, nullptr,
                                                   sim, CHUNK, NNEG, PROJ, nullptr, nullptr);
        topk_loss<<<CHUNK, 256, 0, stream>>>(sim, Z, z2v, c * CHUNK, rowloss);
    }
    loss_reduce<<<1, 256, 0, stream>>>(rowloss, out);
}

// Round 3
// 1716.456 us; speedup vs baseline: 5.7342x; 1.7989x over previous
//
#include <hip/hip_runtime.h>
#include <hip/hip_bf16.h>
#include <math.h>

#define BATCH 4096
#define NNEG 32768
#define HID 1024
#define PROJ 256
#define TOPK 128
#define ROWS_TOTAL 40960
#define CHUNK 1024
#define INV_T 14.2857142857142857f  // 1/0.07

#define BM 128
#define BN 128
#define BK 64
#define LDK 72   // padded LDS row stride (elements)

typedef __attribute__((ext_vector_type(8))) short bf16x8;
typedef __attribute__((ext_vector_type(4))) float f32x4;

// ---------- helpers ----------
__device__ __forceinline__ float b2f(unsigned short u) {
    return __uint_as_float(((unsigned)u) << 16);
}
__device__ __forceinline__ unsigned short f2b(float f) {
    unsigned u = __float_as_uint(f);
    unsigned r = (u + 0x7FFFu + ((u >> 16) & 1u)) >> 16;  // RNE
    return (unsigned short)r;
}
__device__ __forceinline__ float gelu_exact(float v) {
    return 0.5f * v * (1.0f + erff(v * 0.70710678118654752f));
}

__device__ __forceinline__ float blockReduceSumF(float v, volatile float* scratch) {
    #pragma unroll
    for (int o = 32; o > 0; o >>= 1) v += __shfl_down(v, o);
    int wid = threadIdx.x >> 6, lane = threadIdx.x & 63;
    __syncthreads();
    if (lane == 0) scratch[wid] = v;
    __syncthreads();
    return scratch[0] + scratch[1] + scratch[2] + scratch[3];
}

// ---------- fp32 -> bf16 conversion (4 elems/thread) ----------
__global__ __launch_bounds__(256) void conv_f2b(const float* __restrict__ src,
                                                unsigned short* __restrict__ dst, int n)
{
    int i = (blockIdx.x * 256 + threadIdx.x) * 4;
    if (i + 3 < n) {
        float4 v = *(const float4*)(src + i);
        ushort4 o;
        o.x = f2b(v.x); o.y = f2b(v.y); o.z = f2b(v.z); o.w = f2b(v.w);
        *(ushort4*)(dst + i) = o;
    }
}

// ---------- MFMA GEMM: C[M,N] = act(A[M,K]) @ Bw[N,K]^T + bias ----------
// AMODE 0: A is bf16 (ushort), copied as-is.
// AMODE 1: A is fp32, converted to bf16 during staging.
// AMODE 2: A is bf16; BN (scale/shift per k) + exact GELU applied, re-converted.
template<int AMODE, bool OUT_BF16>
__global__ __launch_bounds__(256) void mfma_gemm(
    const void* __restrict__ Av, const unsigned short* __restrict__ Bw,
    const float* __restrict__ bias, void* __restrict__ Cv,
    int M, int N, int K,
    const float* __restrict__ bnscale, const float* __restrict__ bnshift)
{
    __shared__ unsigned short As[BM * LDK];
    __shared__ unsigned short Bs[BN * LDK];
    const int tid = threadIdx.x;
    const int bm = blockIdx.y * BM;
    const int bn = blockIdx.x * BN;
    const int wave = tid >> 6;
    const int lane = tid & 63;
    const int wm = (wave >> 1) * 64;
    const int wn = (wave & 1) * 64;
    const int fr = lane & 15;   // A-row / B-col / C-col
    const int fg = lane >> 4;   // k-group
    const int srow = tid >> 1;            // staging row 0..127
    const int scol = (tid & 1) * 32;      // staging col base

    f32x4 acc[4][4] = {};

    for (int k0 = 0; k0 < K; k0 += BK) {
        // ---- stage A tile [BM][BK] ----
        if (AMODE == 0) {
            const unsigned short* A = (const unsigned short*)Av;
            const uint4* src = (const uint4*)(A + (size_t)(bm + srow) * K + k0 + scol);
            uint4 v0 = src[0], v1 = src[1], v2 = src[2], v3 = src[3];
            uint4* dst = (uint4*)&As[srow * LDK + scol];
            dst[0] = v0; dst[1] = v1; dst[2] = v2; dst[3] = v3;
        } else if (AMODE == 1) {
            const float* A = (const float*)Av;
            const float* src = A + (size_t)(bm + srow) * K + k0 + scol;
            union { unsigned short us[32]; uint4 u4[4]; } tmp;
            #pragma unroll
            for (int j = 0; j < 32; j += 4) {
                float4 v = *(const float4*)(src + j);
                tmp.us[j+0] = f2b(v.x); tmp.us[j+1] = f2b(v.y);
                tmp.us[j+2] = f2b(v.z); tmp.us[j+3] = f2b(v.w);
            }
            uint4* dst = (uint4*)&As[srow * LDK + scol];
            #pragma unroll
            for (int j = 0; j < 4; j++) dst[j] = tmp.u4[j];
        } else {
            const unsigned short* A = (const unsigned short*)Av;
            const uint4* src = (const uint4*)(A + (size_t)(bm + srow) * K + k0 + scol);
            union { unsigned short us[32]; uint4 u4[4]; } raw, tmp;
            #pragma unroll
            for (int j = 0; j < 4; j++) raw.u4[j] = src[j];
            #pragma unroll
            for (int j = 0; j < 32; j++) {
                int kc = k0 + scol + j;
                float v = b2f(raw.us[j]);
                v = fmaf(v, bnscale[kc], bnshift[kc]);
                tmp.us[j] = f2b(gelu_exact(v));
            }
            uint4* dst = (uint4*)&As[srow * LDK + scol];
            #pragma unroll
            for (int j = 0; j < 4; j++) dst[j] = tmp.u4[j];
        }
        // ---- stage B tile [BN][BK] ----
        {
            const uint4* src = (const uint4*)(Bw + (size_t)(bn + srow) * K + k0 + scol);
            uint4 v0 = src[0], v1 = src[1], v2 = src[2], v3 = src[3];
            uint4* dst = (uint4*)&Bs[srow * LDK + scol];
            dst[0] = v0; dst[1] = v1; dst[2] = v2; dst[3] = v3;
        }
        __syncthreads();
        // ---- MFMA ----
        #pragma unroll
        for (int ks = 0; ks < 2; ks++) {
            bf16x8 a[4], b[4];
            #pragma unroll
            for (int mi = 0; mi < 4; mi++)
                a[mi] = *(const bf16x8*)&As[(wm + mi * 16 + fr) * LDK + ks * 32 + fg * 8];
            #pragma unroll
            for (int ni = 0; ni < 4; ni++)
                b[ni] = *(const bf16x8*)&Bs[(wn + ni * 16 + fr) * LDK + ks * 32 + fg * 8];
            #pragma unroll
            for (int mi = 0; mi < 4; mi++)
                #pragma unroll
                for (int ni = 0; ni < 4; ni++)
                    acc[mi][ni] = __builtin_amdgcn_mfma_f32_16x16x32_bf16(a[mi], b[ni], acc[mi][ni], 0, 0, 0);
        }
        __syncthreads();
    }

    // ---- epilogue: C/D layout col=lane&15, row=(lane>>4)*4+reg ----
    #pragma unroll
    for (int mi = 0; mi < 4; mi++) {
        #pragma unroll
        for (int ni = 0; ni < 4; ni++) {
            int col = bn + wn + ni * 16 + fr;
            int row0 = bm + wm + mi * 16 + fg * 4;
            float bv = bias ? bias[col] : 0.0f;
            #pragma unroll
            for (int r = 0; r < 4; r++) {
                float v = acc[mi][ni][r] + bv;
                if (OUT_BF16) {
                    ((unsigned short*)Cv)[(size_t)(row0 + r) * N + col] = f2b(v);
                } else {
                    ((float*)Cv)[(size_t)(row0 + r) * N + col] = v;
                }
            }
        }
    }
}

// ---------- BN stats over bf16 Y: block = 128 rows x 1024 cols ----------
__global__ __launch_bounds__(256) void bn_stats(const unsigned short* __restrict__ Yb, int rows,
                                                float* __restrict__ sum, float* __restrict__ sumsq)
{
    int cg = (threadIdx.x & 127) * 8;
    int r = blockIdx.x * 128 + (threadIdx.x >> 7);
    float s[8] = {}, ss[8] = {};
    for (int i = 0; i < 64; i++, r += 2) {
        uint4 v = *(const uint4*)&Yb[(size_t)r * HID + cg];
        const unsigned short* u = (const unsigned short*)&v;
        #pragma unroll
        for (int j = 0; j < 8; j++) {
            float f = b2f(u[j]);
            s[j] += f; ss[j] += f * f;
        }
    }
    #pragma unroll
    for (int j = 0; j < 8; j++) {
        atomicAdd(&sum[cg + j], s[j]);
        atomicAdd(&sumsq[cg + j], ss[j]);
    }
}

__global__ void bn_finalize(const float* __restrict__ sum, const float* __restrict__ sumsq,
                            const float* __restrict__ gamma, const float* __restrict__ beta,
                            float* __restrict__ scale, float* __restrict__ shift)
{
    int seg = blockIdx.y;
    int col = blockIdx.x * 256 + threadIdx.x;
    float n = (seg == 2) ? (float)NNEG : (float)BATCH;
    float mu = sum[seg * HID + col] / n;
    float var = sumsq[seg * HID + col] / n - mu * mu;
    float sc = gamma[col] * rsqrtf(var + 1e-5f);
    scale[seg * HID + col] = sc;
    shift[seg * HID + col] = beta[col] - mu * sc;
}

// ---------- L2 normalize rows of Z [rows x 256]; write fp32 + bf16 ----------
__global__ __launch_bounds__(256) void l2norm(float* __restrict__ Z, unsigned short* __restrict__ Zb)
{
    __shared__ float scratch[4];
    size_t r = blockIdx.x;
    float v = Z[r * PROJ + threadIdx.x];
    float t = blockReduceSumF(v * v, scratch);
    float scale = 1.0f / fmaxf(sqrtf(t), 1e-12f);
    float o = v * scale;
    Z[r * PROJ + threadIdx.x] = o;
    Zb[r * PROJ + threadIdx.x] = f2b(o);
}

// ---------- fused single-pass hist+expsum top-k loss ----------
// One block per sim row (bf16). 4096-bucket monotone quantization of sim value;
// per-bucket count + sum of exp(v/T - m). Suffix scan finds the K-th bucket;
// tie bucket contributes (K - cgt) * mean(exp) of the bucket.
__global__ __launch_bounds__(256) void topk_loss(
    const unsigned short* __restrict__ simb,   // [CHUNK x NNEG]
    const float* __restrict__ z1, const float* __restrict__ z2,
    int rowOffset, float* __restrict__ rowloss)
{
    __shared__ int   hcnt[4096];
    __shared__ float hsum[4096];
    __shared__ int   segc[256];
    __shared__ float segs[256];
    __shared__ int   sufc[256];
    __shared__ float sufs[256];
    __shared__ float fscratch[4];
    __shared__ int   sel_seg;

    const int tid = threadIdx.x;
    const int grow = rowOffset + blockIdx.x;
    const unsigned short* srow = simb + (size_t)blockIdx.x * NNEG;

    #pragma unroll
    for (int j = 0; j < 16; j++) { hcnt[tid * 16 + j] = 0; hsum[tid * 16 + j] = 0.f; }

    // positive similarity (fp32 z); contains syncthreads (also orders hist zeroing)
    float p = z1[(size_t)grow * PROJ + tid] * z2[(size_t)grow * PROJ + tid];
    float pos = blockReduceSumF(p, fscratch);
    __syncthreads();

    const float m = INV_T;
    // single pass: histogram + per-bucket exp sums
    for (int i = tid * 8; i < NNEG; i += 256 * 8) {
        uint4 v4 = *(const uint4*)(srow + i);
        const unsigned short* u = (const unsigned short*)&v4;
        #pragma unroll
        for (int j = 0; j < 8; j++) {
            float v = b2f(u[j]);
            float e = __expf(fmaf(v, INV_T, -m));
            int k = (int)fmaf(v, 2048.f, 2048.f);
            k = min(max(k, 0), 4095);
            atomicAdd(&hcnt[k], 1);
            atomicAdd(&hsum[k], e);
        }
    }
    __syncthreads();

    // per-segment totals (segment t = bins [16t, 16t+15])
    int c = 0; float s = 0.f;
    #pragma unroll
    for (int j = 0; j < 16; j++) { c += hcnt[tid * 16 + j]; s += hsum[tid * 16 + j]; }
    segc[tid] = c; segs[tid] = s;
    sufc[tid] = c; sufs[tid] = s;
    __syncthreads();
    // inclusive suffix scan over segments
    for (int st = 1; st < 256; st <<= 1) {
        int   aC = (tid + st < 256) ? sufc[tid + st] : 0;
        float aS = (tid + st < 256) ? sufs[tid + st] : 0.f;
        __syncthreads();
        sufc[tid] += aC; sufs[tid] += aS;
        __syncthreads();
    }
    // unique segment containing the K-th largest
    if (sufc[tid] >= TOPK && sufc[tid] - segc[tid] < TOPK) sel_seg = tid;
    __syncthreads();

    if (tid == 0) {
        int t = sel_seg;
        int running = sufc[t] - segc[t];       // count strictly above segment t
        float sumab = sufs[t] - segs[t];       // expsum strictly above segment t
        int bt = t * 16;
        for (int j = 15; j >= 0; j--) {
            int b = t * 16 + j;
            int cb = hcnt[b];
            if (running + cb >= TOPK) { bt = b; break; }
            running += cb; sumab += hsum[b];
        }
        int need = TOPK - running;
        float avg = hsum[bt] / (float)hcnt[bt];
        float total = sumab + (float)need * avg + __expf(fmaf(pos, INV_T, -m));
        rowloss[grow] = m + logf(total) - pos * INV_T;
    }
}

__global__ __launch_bounds__(256) void loss_reduce(const float* __restrict__ rowloss,
                                                   float* __restrict__ out)
{
    __shared__ float scratch[4];
    float s = 0.f;
    for (int i = threadIdx.x; i < BATCH; i += 256) s += rowloss[i];
    s = blockReduceSumF(s, scratch);
    if (threadIdx.x == 0) out[0] = s / (float)BATCH;
}

// ---------- launcher ----------
extern "C" void kernel_launch(void* const* d_in, const int* in_sizes, int n_in,
                              void* d_out, int out_size, void* d_ws, size_t ws_size,
                              hipStream_t stream)
{
    const float* h1    = (const float*)d_in[0];
    const float* h2    = (const float*)d_in[1];
    const float* hneg  = (const float*)d_in[2];
    const float* W1    = (const float*)d_in[3];
    const float* b1    = (const float*)d_in[4];
    const float* gamma = (const float*)d_in[5];
    const float* beta  = (const float*)d_in[6];
    const float* W2    = (const float*)d_in[7];
    const float* b2    = (const float*)d_in[8];
    float* out = (float*)d_out;
    float* ws  = (float*)d_ws;

    // workspace layout (float offsets)
    unsigned short* Yb  = (unsigned short*)ws;                    // 40960x1024 bf16 = 20,971,520 f
    float*          Z   = ws + 20971520;                          // 40960x256 f32   = 10,485,760 f
    unsigned short* Zb  = (unsigned short*)(ws + 31457280);       // 40960x256 bf16  =  5,242,880 f
    unsigned short* W1b = (unsigned short*)(ws + 36700160);       // 1M bf16         =    524,288 f
    unsigned short* W2b = (unsigned short*)(ws + 37224448);       // 256K bf16       =    131,072 f
    float* s_sum   = ws + 37355520;                               // 3*1024
    float* s_sumsq = s_sum + 3072;
    float* s_scale = s_sum + 6144;
    float* s_shift = s_sum + 9216;
    float* rowloss = ws + 37367808;                               // 4096
    unsigned short* simb = (unsigned short*)ws;                   // overlay Yb (dead after GEMM2):
                                                                  // CHUNK x NNEG bf16 = 64 MB < 84 MB

    hipMemsetAsync(s_sum, 0, 2 * 3072 * sizeof(float), stream);

    // weights -> bf16
    conv_f2b<<<1024, 256, 0, stream>>>(W1, W1b, HID * HID);
    conv_f2b<<<256, 256, 0, stream>>>(W2, W2b, PROJ * HID);

    const float* xs[3]   = { h1, h2, hneg };
    const int    rows[3] = { BATCH, BATCH, NNEG };
    const int    yoff[3] = { 0, BATCH, 2 * BATCH };

    // GEMM1: Yb = bf16(X) @ W1b^T + b1
    for (int s = 0; s < 3; s++) {
        dim3 g(HID / BN, rows[s] / BM);
        mfma_gemm<1, true><<<g, 256, 0, stream>>>(xs[s], W1b, b1,
                                                  Yb + (size_t)yoff[s] * HID,
                                                  rows[s], HID, HID, nullptr, nullptr);
    }
    // BN stats + finalize (scale/shift form)
    for (int s = 0; s < 3; s++) {
        bn_stats<<<rows[s] / 128, 256, 0, stream>>>(Yb + (size_t)yoff[s] * HID, rows[s],
                                                    s_sum + s * HID, s_sumsq + s * HID);
    }
    bn_finalize<<<dim3(HID / 256, 3), 256, 0, stream>>>(s_sum, s_sumsq, gamma, beta, s_scale, s_shift);

    // GEMM2: Z = GELU(BN(Yb)) @ W2b^T + b2
    for (int s = 0; s < 3; s++) {
        dim3 g(PROJ / BN, rows[s] / BM);
        mfma_gemm<2, false><<<g, 256, 0, stream>>>(Yb + (size_t)yoff[s] * HID, W2b, b2,
                                                   Z + (size_t)yoff[s] * PROJ,
                                                   rows[s], PROJ, HID,
                                                   s_scale + s * HID, s_shift + s * HID);
    }
    // L2 normalize (fp32 + bf16 outputs)
    l2norm<<<ROWS_TOTAL, 256, 0, stream>>>(Z, Zb);

    // sim chunks (bf16 sim): sim = z1_chunk @ z_neg^T, then fused hist top-k loss
    const unsigned short* znegb = Zb + (size_t)(2 * BATCH) * PROJ;
    const float* z2v = Z + (size_t)BATCH * PROJ;
    for (int c = 0; c < BATCH / CHUNK; c++) {
        dim3 g(NNEG / BN, CHUNK / BM);
        mfma_gemm<0, true><<<g, 256, 0, stream>>>(Zb + (size_t)(c * CHUNK) * PROJ, znegb, nullptr,
                                                  simb, CHUNK, NNEG, PROJ, nullptr, nullptr);
        topk_loss<<<CHUNK, 256, 0, stream>>>(simb, Z, z2v, c * CHUNK, rowloss);
    }
    loss_reduce<<<1, 256, 0, stream>>>(rowloss, out);
}

// Round 4
// 1629.029 us; speedup vs baseline: 6.0419x; 1.0537x over previous
//
#include <hip/hip_runtime.h>
#include <hip/hip_bf16.h>
#include <math.h>

#define BATCH 4096
#define NNEG 32768
#define HID 1024
#define PROJ 256
#define TOPK 128
#define ROWS_TOTAL 40960
#define CHUNK 1024
#define INV_T 14.2857142857142857f  // 1/0.07

#define BM 128
#define BN 128
#define BK 64
#define LDK 72   // padded LDS row stride (elements)

typedef __attribute__((ext_vector_type(8))) short bf16x8;
typedef __attribute__((ext_vector_type(4))) float f32x4;

// ---------- helpers ----------
__device__ __forceinline__ float b2f(unsigned short u) {
    return __uint_as_float(((unsigned)u) << 16);
}
__device__ __forceinline__ unsigned short f2b(float f) {
    unsigned u = __float_as_uint(f);
    unsigned r = (u + 0x7FFFu + ((u >> 16) & 1u)) >> 16;  // RNE
    return (unsigned short)r;
}
__device__ __forceinline__ float gelu_exact(float v) {
    return 0.5f * v * (1.0f + erff(v * 0.70710678118654752f));
}

__device__ __forceinline__ float blockReduceSumF(float v, volatile float* scratch) {
    #pragma unroll
    for (int o = 32; o > 0; o >>= 1) v += __shfl_down(v, o);
    int wid = threadIdx.x >> 6, lane = threadIdx.x & 63;
    __syncthreads();
    if (lane == 0) scratch[wid] = v;
    __syncthreads();
    return scratch[0] + scratch[1] + scratch[2] + scratch[3];
}

// ---------- fp32 -> bf16 conversion ----------
__global__ __launch_bounds__(256) void conv_f2b(const float* __restrict__ src,
                                                unsigned short* __restrict__ dst, int n)
{
    int i = (blockIdx.x * 256 + threadIdx.x) * 4;
    if (i + 3 < n) {
        float4 v = *(const float4*)(src + i);
        ushort4 o;
        o.x = f2b(v.x); o.y = f2b(v.y); o.z = f2b(v.z); o.w = f2b(v.w);
        *(ushort4*)(dst + i) = o;
    }
}

// 8 elems/thread version for the big h_neg conversion
__global__ __launch_bounds__(256) void conv_f2b8(const float* __restrict__ src,
                                                 unsigned short* __restrict__ dst)
{
    int i = (blockIdx.x * 256 + threadIdx.x) * 8;
    float4 a = *(const float4*)(src + i);
    float4 b = *(const float4*)(src + i + 4);
    ushort4 o0, o1;
    o0.x = f2b(a.x); o0.y = f2b(a.y); o0.z = f2b(a.z); o0.w = f2b(a.w);
    o1.x = f2b(b.x); o1.y = f2b(b.y); o1.z = f2b(b.z); o1.w = f2b(b.w);
    *(ushort4*)(dst + i) = o0;
    *(ushort4*)(dst + i + 4) = o1;
}

// ---------- XCD-chunked bijective swizzle (nwg % 8 == 0 in all launches) ----------
__device__ __forceinline__ void xcd_swizzle(int& bx, int& by) {
    int gx = gridDim.x;
    int orig = by * gx + bx;
    int q = (gx * gridDim.y) >> 3;
    int wg = (orig & 7) * q + (orig >> 3);
    bx = wg % gx;
    by = wg / gx;
}

// ---------- MFMA GEMM: C[M,N] = act(A[M,K]) @ Bw[N,K]^T + bias ----------
// AMODE 0: A is bf16 (ushort), copied as-is.
// AMODE 1: A is fp32, converted to bf16 during staging.
// AMODE 2: A is bf16; BN (scale/shift per k) + exact GELU applied, re-converted.
template<int AMODE, bool OUT_BF16>
__global__ __launch_bounds__(256) void mfma_gemm(
    const void* __restrict__ Av, const unsigned short* __restrict__ Bw,
    const float* __restrict__ bias, void* __restrict__ Cv,
    int M, int N, int K,
    const float* __restrict__ bnscale, const float* __restrict__ bnshift)
{
    __shared__ unsigned short As[BM * LDK];
    __shared__ unsigned short Bs[BN * LDK];
    const int tid = threadIdx.x;
    int bxi = blockIdx.x, byi = blockIdx.y;
    xcd_swizzle(bxi, byi);
    const int bm = byi * BM;
    const int bn = bxi * BN;
    const int wave = tid >> 6;
    const int lane = tid & 63;
    const int wm = (wave >> 1) * 64;
    const int wn = (wave & 1) * 64;
    const int fr = lane & 15;   // A-row / B-col / C-col
    const int fg = lane >> 4;   // k-group
    const int srow = tid >> 1;            // staging row 0..127
    const int scol = (tid & 1) * 32;      // staging col base

    f32x4 acc[4][4] = {};

    for (int k0 = 0; k0 < K; k0 += BK) {
        // ---- stage A tile [BM][BK] ----
        if (AMODE == 0) {
            const unsigned short* A = (const unsigned short*)Av;
            const uint4* src = (const uint4*)(A + (size_t)(bm + srow) * K + k0 + scol);
            uint4 v0 = src[0], v1 = src[1], v2 = src[2], v3 = src[3];
            uint4* dst = (uint4*)&As[srow * LDK + scol];
            dst[0] = v0; dst[1] = v1; dst[2] = v2; dst[3] = v3;
        } else if (AMODE == 1) {
            const float* A = (const float*)Av;
            const float* src = A + (size_t)(bm + srow) * K + k0 + scol;
            union { unsigned short us[32]; uint4 u4[4]; } tmp;
            #pragma unroll
            for (int j = 0; j < 32; j += 4) {
                float4 v = *(const float4*)(src + j);
                tmp.us[j+0] = f2b(v.x); tmp.us[j+1] = f2b(v.y);
                tmp.us[j+2] = f2b(v.z); tmp.us[j+3] = f2b(v.w);
            }
            uint4* dst = (uint4*)&As[srow * LDK + scol];
            #pragma unroll
            for (int j = 0; j < 4; j++) dst[j] = tmp.u4[j];
        } else {
            const unsigned short* A = (const unsigned short*)Av;
            const uint4* src = (const uint4*)(A + (size_t)(bm + srow) * K + k0 + scol);
            union { unsigned short us[32]; uint4 u4[4]; } raw, tmp;
            #pragma unroll
            for (int j = 0; j < 4; j++) raw.u4[j] = src[j];
            #pragma unroll
            for (int j = 0; j < 32; j++) {
                int kc = k0 + scol + j;
                float v = b2f(raw.us[j]);
                v = fmaf(v, bnscale[kc], bnshift[kc]);
                tmp.us[j] = f2b(gelu_exact(v));
            }
            uint4* dst = (uint4*)&As[srow * LDK + scol];
            #pragma unroll
            for (int j = 0; j < 4; j++) dst[j] = tmp.u4[j];
        }
        // ---- stage B tile [BN][BK] ----
        {
            const uint4* src = (const uint4*)(Bw + (size_t)(bn + srow) * K + k0 + scol);
            uint4 v0 = src[0], v1 = src[1], v2 = src[2], v3 = src[3];
            uint4* dst = (uint4*)&Bs[srow * LDK + scol];
            dst[0] = v0; dst[1] = v1; dst[2] = v2; dst[3] = v3;
        }
        __syncthreads();
        // ---- MFMA ----
        #pragma unroll
        for (int ks = 0; ks < 2; ks++) {
            bf16x8 a[4], b[4];
            #pragma unroll
            for (int mi = 0; mi < 4; mi++)
                a[mi] = *(const bf16x8*)&As[(wm + mi * 16 + fr) * LDK + ks * 32 + fg * 8];
            #pragma unroll
            for (int ni = 0; ni < 4; ni++)
                b[ni] = *(const bf16x8*)&Bs[(wn + ni * 16 + fr) * LDK + ks * 32 + fg * 8];
            #pragma unroll
            for (int mi = 0; mi < 4; mi++)
                #pragma unroll
                for (int ni = 0; ni < 4; ni++)
                    acc[mi][ni] = __builtin_amdgcn_mfma_f32_16x16x32_bf16(a[mi], b[ni], acc[mi][ni], 0, 0, 0);
        }
        __syncthreads();
    }

    // ---- epilogue: C/D layout col=lane&15, row=(lane>>4)*4+reg ----
    #pragma unroll
    for (int mi = 0; mi < 4; mi++) {
        #pragma unroll
        for (int ni = 0; ni < 4; ni++) {
            int col = bn + wn + ni * 16 + fr;
            int row0 = bm + wm + mi * 16 + fg * 4;
            float bv = bias ? bias[col] : 0.0f;
            #pragma unroll
            for (int r = 0; r < 4; r++) {
                float v = acc[mi][ni][r] + bv;
                if (OUT_BF16) {
                    ((unsigned short*)Cv)[(size_t)(row0 + r) * N + col] = f2b(v);
                } else {
                    ((float*)Cv)[(size_t)(row0 + r) * N + col] = v;
                }
            }
        }
    }
}

// ---------- BN stats over bf16 Y: block = 128 rows x 1024 cols ----------
__global__ __launch_bounds__(256) void bn_stats(const unsigned short* __restrict__ Yb, int rows,
                                                float* __restrict__ sum, float* __restrict__ sumsq)
{
    int cg = (threadIdx.x & 127) * 8;
    int r = blockIdx.x * 128 + (threadIdx.x >> 7);
    float s[8] = {}, ss[8] = {};
    for (int i = 0; i < 64; i++, r += 2) {
        uint4 v = *(const uint4*)&Yb[(size_t)r * HID + cg];
        const unsigned short* u = (const unsigned short*)&v;
        #pragma unroll
        for (int j = 0; j < 8; j++) {
            float f = b2f(u[j]);
            s[j] += f; ss[j] += f * f;
        }
    }
    #pragma unroll
    for (int j = 0; j < 8; j++) {
        atomicAdd(&sum[cg + j], s[j]);
        atomicAdd(&sumsq[cg + j], ss[j]);
    }
}

__global__ void bn_finalize(const float* __restrict__ sum, const float* __restrict__ sumsq,
                            const float* __restrict__ gamma, const float* __restrict__ beta,
                            float* __restrict__ scale, float* __restrict__ shift)
{
    int seg = blockIdx.y;
    int col = blockIdx.x * 256 + threadIdx.x;
    float n = (seg == 2) ? (float)NNEG : (float)BATCH;
    float mu = sum[seg * HID + col] / n;
    float var = sumsq[seg * HID + col] / n - mu * mu;
    float sc = gamma[col] * rsqrtf(var + 1e-5f);
    scale[seg * HID + col] = sc;
    shift[seg * HID + col] = beta[col] - mu * sc;
}

// ---------- L2 normalize rows; read bf16 pre-norm, write bf16 all + fp32 first 8192 ----------
__global__ __launch_bounds__(256) void l2norm(const unsigned short* __restrict__ Zpre,
                                              unsigned short* __restrict__ Zb,
                                              float* __restrict__ Zfp)
{
    __shared__ float scratch[4];
    size_t r = blockIdx.x;
    float v = b2f(Zpre[r * PROJ + threadIdx.x]);
    float t = blockReduceSumF(v * v, scratch);
    float scale = 1.0f / fmaxf(sqrtf(t), 1e-12f);
    float o = v * scale;
    Zb[r * PROJ + threadIdx.x] = f2b(o);
    if (r < 2 * BATCH) Zfp[r * PROJ + threadIdx.x] = o;
}

// ---------- fused single-pass hist+expsum top-k loss ----------
__global__ __launch_bounds__(256) void topk_loss(
    const unsigned short* __restrict__ simb,   // [CHUNK x NNEG]
    const float* __restrict__ z1, const float* __restrict__ z2,
    int rowOffset, float* __restrict__ rowloss)
{
    __shared__ int   hcnt[4096];
    __shared__ float hsum[4096];
    __shared__ int   segc[256];
    __shared__ float segs[256];
    __shared__ int   sufc[256];
    __shared__ float sufs[256];
    __shared__ float fscratch[4];
    __shared__ int   sel_seg;

    const int tid = threadIdx.x;
    const int grow = rowOffset + blockIdx.x;
    const unsigned short* srow = simb + (size_t)blockIdx.x * NNEG;

    #pragma unroll
    for (int j = 0; j < 16; j++) { hcnt[tid * 16 + j] = 0; hsum[tid * 16 + j] = 0.f; }

    // positive similarity (fp32 z); contains syncthreads (also orders hist zeroing)
    float p = z1[(size_t)grow * PROJ + tid] * z2[(size_t)grow * PROJ + tid];
    float pos = blockReduceSumF(p, fscratch);
    __syncthreads();

    const float m = INV_T;
    // single pass: histogram + per-bucket exp sums
    for (int i = tid * 8; i < NNEG; i += 256 * 8) {
        uint4 v4 = *(const uint4*)(srow + i);
        const unsigned short* u = (const unsigned short*)&v4;
        #pragma unroll
        for (int j = 0; j < 8; j++) {
            float v = b2f(u[j]);
            float e = __expf(fmaf(v, INV_T, -m));
            int k = (int)fmaf(v, 2048.f, 2048.f);
            k = min(max(k, 0), 4095);
            atomicAdd(&hcnt[k], 1);
            atomicAdd(&hsum[k], e);
        }
    }
    __syncthreads();

    // per-segment totals (segment t = bins [16t, 16t+15])
    int c = 0; float s = 0.f;
    #pragma unroll
    for (int j = 0; j < 16; j++) { c += hcnt[tid * 16 + j]; s += hsum[tid * 16 + j]; }
    segc[tid] = c; segs[tid] = s;
    sufc[tid] = c; sufs[tid] = s;
    __syncthreads();
    // inclusive suffix scan over segments
    for (int st = 1; st < 256; st <<= 1) {
        int   aC = (tid + st < 256) ? sufc[tid + st] : 0;
        float aS = (tid + st < 256) ? sufs[tid + st] : 0.f;
        __syncthreads();
        sufc[tid] += aC; sufs[tid] += aS;
        __syncthreads();
    }
    // unique segment containing the K-th largest
    if (sufc[tid] >= TOPK && sufc[tid] - segc[tid] < TOPK) sel_seg = tid;
    __syncthreads();

    if (tid == 0) {
        int t = sel_seg;
        int running = sufc[t] - segc[t];       // count strictly above segment t
        float sumab = sufs[t] - segs[t];       // expsum strictly above segment t
        int bt = t * 16;
        for (int j = 15; j >= 0; j--) {
            int b = t * 16 + j;
            int cb = hcnt[b];
            if (running + cb >= TOPK) { bt = b; break; }
            running += cb; sumab += hsum[b];
        }
        int need = TOPK - running;
        float avg = hsum[bt] / (float)hcnt[bt];
        float total = sumab + (float)need * avg + __expf(fmaf(pos, INV_T, -m));
        rowloss[grow] = m + logf(total) - pos * INV_T;
    }
}

__global__ __launch_bounds__(256) void loss_reduce(const float* __restrict__ rowloss,
                                                   float* __restrict__ out)
{
    __shared__ float scratch[4];
    float s = 0.f;
    for (int i = threadIdx.x; i < BATCH; i += 256) s += rowloss[i];
    s = blockReduceSumF(s, scratch);
    if (threadIdx.x == 0) out[0] = s / (float)BATCH;
}

// ---------- launcher ----------
extern "C" void kernel_launch(void* const* d_in, const int* in_sizes, int n_in,
                              void* d_out, int out_size, void* d_ws, size_t ws_size,
                              hipStream_t stream)
{
    const float* h1    = (const float*)d_in[0];
    const float* h2    = (const float*)d_in[1];
    const float* hneg  = (const float*)d_in[2];
    const float* W1    = (const float*)d_in[3];
    const float* b1    = (const float*)d_in[4];
    const float* gamma = (const float*)d_in[5];
    const float* beta  = (const float*)d_in[6];
    const float* W2    = (const float*)d_in[7];
    const float* b2    = (const float*)d_in[8];
    float* out = (float*)d_out;
    float* ws  = (float*)d_ws;

    // workspace layout (float offsets); total 51,003,392 f = 204 MB
    unsigned short* hneg_b = (unsigned short*)ws;                 // 32768x1024 bf16 = 16,777,216 f
    unsigned short* Yb   = (unsigned short*)(ws + 16777216);      // 40960x1024 bf16 = 20,971,520 f
    unsigned short* Zpre = (unsigned short*)(ws + 37748736);      // 40960x256 bf16  =  5,242,880 f
    unsigned short* Zb   = (unsigned short*)(ws + 42991616);      // 40960x256 bf16  =  5,242,880 f
    float*          Zfp  = ws + 48234496;                         // 8192x256 f32    =  2,097,152 f
    unsigned short* W1b  = (unsigned short*)(ws + 50331648);      // 1M bf16         =    524,288 f
    unsigned short* W2b  = (unsigned short*)(ws + 50855936);      // 256K bf16       =    131,072 f
    float* s_sum   = ws + 50987008;                               // 3*1024 x4
    float* s_sumsq = s_sum + 3072;
    float* s_scale = s_sum + 6144;
    float* s_shift = s_sum + 9216;
    float* rowloss = ws + 50999296;                               // 4096
    unsigned short* simb = hneg_b;                                // overlay (dead after GEMM1-hneg):
                                                                  // CHUNK x NNEG bf16 = 64 MB (exact fit)

    hipMemsetAsync(s_sum, 0, 2 * 3072 * sizeof(float), stream);

    // conversions: weights + h_neg -> bf16
    conv_f2b<<<1024, 256, 0, stream>>>(W1, W1b, HID * HID);
    conv_f2b<<<256, 256, 0, stream>>>(W2, W2b, PROJ * HID);
    conv_f2b8<<<16384, 256, 0, stream>>>(hneg, hneg_b);

    // GEMM1: Yb = bf16(X) @ W1b^T + b1
    {
        dim3 g(HID / BN, BATCH / BM);
        mfma_gemm<1, true><<<g, 256, 0, stream>>>(h1, W1b, b1, Yb, BATCH, HID, HID, nullptr, nullptr);
        mfma_gemm<1, true><<<g, 256, 0, stream>>>(h2, W1b, b1, Yb + (size_t)BATCH * HID,
                                                  BATCH, HID, HID, nullptr, nullptr);
        dim3 gn(HID / BN, NNEG / BM);
        mfma_gemm<0, true><<<gn, 256, 0, stream>>>(hneg_b, W1b, b1, Yb + (size_t)2 * BATCH * HID,
                                                   NNEG, HID, HID, nullptr, nullptr);
    }

    const int rows[3] = { BATCH, BATCH, NNEG };
    const int yoff[3] = { 0, BATCH, 2 * BATCH };

    // BN stats + finalize (scale/shift form)
    for (int s = 0; s < 3; s++) {
        bn_stats<<<rows[s] / 128, 256, 0, stream>>>(Yb + (size_t)yoff[s] * HID, rows[s],
                                                    s_sum + s * HID, s_sumsq + s * HID);
    }
    bn_finalize<<<dim3(HID / 256, 3), 256, 0, stream>>>(s_sum, s_sumsq, gamma, beta, s_scale, s_shift);

    // GEMM2: Zpre = GELU(BN(Yb)) @ W2b^T + b2 (bf16 out)
    for (int s = 0; s < 3; s++) {
        dim3 g(PROJ / BN, rows[s] / BM);
        mfma_gemm<2, true><<<g, 256, 0, stream>>>(Yb + (size_t)yoff[s] * HID, W2b, b2,
                                                  Zpre + (size_t)yoff[s] * PROJ,
                                                  rows[s], PROJ, HID,
                                                  s_scale + s * HID, s_shift + s * HID);
    }
    // L2 normalize
    l2norm<<<ROWS_TOTAL, 256, 0, stream>>>(Zpre, Zb, Zfp);

    // sim chunks (bf16 sim): sim = z1_chunk @ z_neg^T, then fused hist top-k loss
    const unsigned short* znegb = Zb + (size_t)(2 * BATCH) * PROJ;
    const float* z2v = Zfp + (size_t)BATCH * PROJ;
    for (int c = 0; c < BATCH / CHUNK; c++) {
        dim3 g(NNEG / BN, CHUNK / BM);
        mfma_gemm<0, true><<<g, 256, 0, stream>>>(Zb + (size_t)(c * CHUNK) * PROJ, znegb, nullptr,
                                                  simb, CHUNK, NNEG, PROJ, nullptr, nullptr);
        topk_loss<<<CHUNK, 256, 0, stream>>>(simb, Zfp, z2v, c * CHUNK, rowloss);
    }
    loss_reduce<<<1, 256, 0, stream>>>(rowloss, out);
}

// Round 5
// 1380.997 us; speedup vs baseline: 7.1271x; 1.1796x over previous
//
#include <hip/hip_runtime.h>
#include <hip/hip_bf16.h>
#include <math.h>

#define BATCH 4096
#define NNEG 32768
#define HID 1024
#define PROJ 256
#define TOPK 128
#define ROWS_TOTAL 40960
#define CHUNK 1024
#define INV_T 14.2857142857142857f  // 1/0.07

#define BM 128
#define BN 128
#define BK 64
#define LDK 72   // padded LDS row stride (elements)

typedef __attribute__((ext_vector_type(8))) short bf16x8;
typedef __attribute__((ext_vector_type(4))) float f32x4;

// ---------- helpers ----------
__device__ __forceinline__ float b2f(unsigned short u) {
    return __uint_as_float(((unsigned)u) << 16);
}
__device__ __forceinline__ unsigned short f2b(float f) {
    unsigned u = __float_as_uint(f);
    unsigned r = (u + 0x7FFFu + ((u >> 16) & 1u)) >> 16;  // RNE
    return (unsigned short)r;
}
__device__ __forceinline__ float gelu_exact(float v) {
    return 0.5f * v * (1.0f + erff(v * 0.70710678118654752f));
}

__device__ __forceinline__ float blockReduceSumF(float v, volatile float* scratch) {
    #pragma unroll
    for (int o = 32; o > 0; o >>= 1) v += __shfl_down(v, o);
    int wid = threadIdx.x >> 6, lane = threadIdx.x & 63;
    __syncthreads();
    if (lane == 0) scratch[wid] = v;
    __syncthreads();
    return scratch[0] + scratch[1] + scratch[2] + scratch[3];
}
__device__ __forceinline__ int blockReduceSumI(int v, volatile int* scratch) {
    #pragma unroll
    for (int o = 32; o > 0; o >>= 1) v += __shfl_down(v, o);
    int wid = threadIdx.x >> 6, lane = threadIdx.x & 63;
    __syncthreads();
    if (lane == 0) scratch[wid] = v;
    __syncthreads();
    return scratch[0] + scratch[1] + scratch[2] + scratch[3];
}

// ---------- fp32 -> bf16 conversion ----------
__global__ __launch_bounds__(256) void conv_f2b(const float* __restrict__ src,
                                                unsigned short* __restrict__ dst, int n)
{
    int i = (blockIdx.x * 256 + threadIdx.x) * 4;
    if (i + 3 < n) {
        float4 v = *(const float4*)(src + i);
        ushort4 o;
        o.x = f2b(v.x); o.y = f2b(v.y); o.z = f2b(v.z); o.w = f2b(v.w);
        *(ushort4*)(dst + i) = o;
    }
}

// 8 elems/thread version for the big h_neg conversion
__global__ __launch_bounds__(256) void conv_f2b8(const float* __restrict__ src,
                                                 unsigned short* __restrict__ dst)
{
    int i = (blockIdx.x * 256 + threadIdx.x) * 8;
    float4 a = *(const float4*)(src + i);
    float4 b = *(const float4*)(src + i + 4);
    ushort4 o0, o1;
    o0.x = f2b(a.x); o0.y = f2b(a.y); o0.z = f2b(a.z); o0.w = f2b(a.w);
    o1.x = f2b(b.x); o1.y = f2b(b.y); o1.z = f2b(b.z); o1.w = f2b(b.w);
    *(ushort4*)(dst + i) = o0;
    *(ushort4*)(dst + i + 4) = o1;
}

// ---------- XCD-chunked bijective swizzle (nwg % 8 == 0 in all launches) ----------
__device__ __forceinline__ void xcd_swizzle(int& bx, int& by) {
    int gx = gridDim.x;
    int orig = by * gx + bx;
    int q = (gx * gridDim.y) >> 3;
    int wg = (orig & 7) * q + (orig >> 3);
    bx = wg % gx;
    by = wg / gx;
}

// ---------- MFMA GEMM: C[M,N] = act(A[M,K]) @ Bw[N,K]^T + bias ----------
// AMODE 0: A is bf16 (ushort), copied as-is.
// AMODE 1: A is fp32, converted to bf16 during staging.
// AMODE 2: A is bf16; BN (scale/shift per k) + exact GELU applied, re-converted.
template<int AMODE, bool OUT_BF16>
__global__ __launch_bounds__(256) void mfma_gemm(
    const void* __restrict__ Av, const unsigned short* __restrict__ Bw,
    const float* __restrict__ bias, void* __restrict__ Cv,
    int M, int N, int K,
    const float* __restrict__ bnscale, const float* __restrict__ bnshift)
{
    __shared__ unsigned short As[BM * LDK];
    __shared__ unsigned short Bs[BN * LDK];
    const int tid = threadIdx.x;
    int bxi = blockIdx.x, byi = blockIdx.y;
    xcd_swizzle(bxi, byi);
    const int bm = byi * BM;
    const int bn = bxi * BN;
    const int wave = tid >> 6;
    const int lane = tid & 63;
    const int wm = (wave >> 1) * 64;
    const int wn = (wave & 1) * 64;
    const int fr = lane & 15;   // A-row / B-col / C-col
    const int fg = lane >> 4;   // k-group
    const int srow = tid >> 1;            // staging row 0..127
    const int scol = (tid & 1) * 32;      // staging col base

    f32x4 acc[4][4] = {};

    for (int k0 = 0; k0 < K; k0 += BK) {
        // ---- stage A tile [BM][BK] ----
        if (AMODE == 0) {
            const unsigned short* A = (const unsigned short*)Av;
            const uint4* src = (const uint4*)(A + (size_t)(bm + srow) * K + k0 + scol);
            uint4 v0 = src[0], v1 = src[1], v2 = src[2], v3 = src[3];
            uint4* dst = (uint4*)&As[srow * LDK + scol];
            dst[0] = v0; dst[1] = v1; dst[2] = v2; dst[3] = v3;
        } else if (AMODE == 1) {
            const float* A = (const float*)Av;
            const float* src = A + (size_t)(bm + srow) * K + k0 + scol;
            union { unsigned short us[32]; uint4 u4[4]; } tmp;
            #pragma unroll
            for (int j = 0; j < 32; j += 4) {
                float4 v = *(const float4*)(src + j);
                tmp.us[j+0] = f2b(v.x); tmp.us[j+1] = f2b(v.y);
                tmp.us[j+2] = f2b(v.z); tmp.us[j+3] = f2b(v.w);
            }
            uint4* dst = (uint4*)&As[srow * LDK + scol];
            #pragma unroll
            for (int j = 0; j < 4; j++) dst[j] = tmp.u4[j];
        } else {
            const unsigned short* A = (const unsigned short*)Av;
            const uint4* src = (const uint4*)(A + (size_t)(bm + srow) * K + k0 + scol);
            union { unsigned short us[32]; uint4 u4[4]; } raw, tmp;
            #pragma unroll
            for (int j = 0; j < 4; j++) raw.u4[j] = src[j];
            #pragma unroll
            for (int j = 0; j < 32; j++) {
                int kc = k0 + scol + j;
                float v = b2f(raw.us[j]);
                v = fmaf(v, bnscale[kc], bnshift[kc]);
                tmp.us[j] = f2b(gelu_exact(v));
            }
            uint4* dst = (uint4*)&As[srow * LDK + scol];
            #pragma unroll
            for (int j = 0; j < 4; j++) dst[j] = tmp.u4[j];
        }
        // ---- stage B tile [BN][BK] ----
        {
            const uint4* src = (const uint4*)(Bw + (size_t)(bn + srow) * K + k0 + scol);
            uint4 v0 = src[0], v1 = src[1], v2 = src[2], v3 = src[3];
            uint4* dst = (uint4*)&Bs[srow * LDK + scol];
            dst[0] = v0; dst[1] = v1; dst[2] = v2; dst[3] = v3;
        }
        __syncthreads();
        // ---- MFMA ----
        #pragma unroll
        for (int ks = 0; ks < 2; ks++) {
            bf16x8 a[4], b[4];
            #pragma unroll
            for (int mi = 0; mi < 4; mi++)
                a[mi] = *(const bf16x8*)&As[(wm + mi * 16 + fr) * LDK + ks * 32 + fg * 8];
            #pragma unroll
            for (int ni = 0; ni < 4; ni++)
                b[ni] = *(const bf16x8*)&Bs[(wn + ni * 16 + fr) * LDK + ks * 32 + fg * 8];
            #pragma unroll
            for (int mi = 0; mi < 4; mi++)
                #pragma unroll
                for (int ni = 0; ni < 4; ni++)
                    acc[mi][ni] = __builtin_amdgcn_mfma_f32_16x16x32_bf16(a[mi], b[ni], acc[mi][ni], 0, 0, 0);
        }
        __syncthreads();
    }

    // ---- epilogue: C/D layout col=lane&15, row=(lane>>4)*4+reg ----
    #pragma unroll
    for (int mi = 0; mi < 4; mi++) {
        #pragma unroll
        for (int ni = 0; ni < 4; ni++) {
            int col = bn + wn + ni * 16 + fr;
            int row0 = bm + wm + mi * 16 + fg * 4;
            float bv = bias ? bias[col] : 0.0f;
            #pragma unroll
            for (int r = 0; r < 4; r++) {
                float v = acc[mi][ni][r] + bv;
                if (OUT_BF16) {
                    ((unsigned short*)Cv)[(size_t)(row0 + r) * N + col] = f2b(v);
                } else {
                    ((float*)Cv)[(size_t)(row0 + r) * N + col] = v;
                }
            }
        }
    }
}

// ---------- BN stats over bf16 Y: block = 32 rows x 1024 cols ----------
__global__ __launch_bounds__(256) void bn_stats(const unsigned short* __restrict__ Yb, int rows,
                                                float* __restrict__ sum, float* __restrict__ sumsq)
{
    int cg = (threadIdx.x & 127) * 8;
    int r = blockIdx.x * 32 + (threadIdx.x >> 7);
    float s[8] = {}, ss[8] = {};
    for (int i = 0; i < 16; i++, r += 2) {
        uint4 v = *(const uint4*)&Yb[(size_t)r * HID + cg];
        const unsigned short* u = (const unsigned short*)&v;
        #pragma unroll
        for (int j = 0; j < 8; j++) {
            float f = b2f(u[j]);
            s[j] += f; ss[j] += f * f;
        }
    }
    #pragma unroll
    for (int j = 0; j < 8; j++) {
        atomicAdd(&sum[cg + j], s[j]);
        atomicAdd(&sumsq[cg + j], ss[j]);
    }
}

__global__ void bn_finalize(const float* __restrict__ sum, const float* __restrict__ sumsq,
                            const float* __restrict__ gamma, const float* __restrict__ beta,
                            float* __restrict__ scale, float* __restrict__ shift)
{
    int seg = blockIdx.y;
    int col = blockIdx.x * 256 + threadIdx.x;
    float n = (seg == 2) ? (float)NNEG : (float)BATCH;
    float mu = sum[seg * HID + col] / n;
    float var = sumsq[seg * HID + col] / n - mu * mu;
    float sc = gamma[col] * rsqrtf(var + 1e-5f);
    scale[seg * HID + col] = sc;
    shift[seg * HID + col] = beta[col] - mu * sc;
}

// ---------- L2 normalize rows; read bf16 pre-norm, write bf16 all + fp32 first 8192 ----------
__global__ __launch_bounds__(256) void l2norm(const unsigned short* __restrict__ Zpre,
                                              unsigned short* __restrict__ Zb,
                                              float* __restrict__ Zfp)
{
    __shared__ float scratch[4];
    size_t r = blockIdx.x;
    float v = b2f(Zpre[r * PROJ + threadIdx.x]);
    float t = blockReduceSumF(v * v, scratch);
    float scale = 1.0f / fmaxf(sqrtf(t), 1e-12f);
    float o = v * scale;
    Zb[r * PROJ + threadIdx.x] = f2b(o);
    if (r < 2 * BATCH) Zfp[r * PROJ + threadIdx.x] = o;
}

// ---------- two-pass hist top-k loss ----------
// Pass 1: count-only histogram (4096 monotone buckets of sim value).
// Suffix scan -> threshold bucket bt, count strictly above.
// Pass 2: exp only for elements in buckets >= bt (~TOPK of NNEG); tie bucket
// contributes need * mean(exp of tie bucket). Same numerics as R4 kernel.
__global__ __launch_bounds__(256) void topk_loss(
    const unsigned short* __restrict__ simb,   // [CHUNK x NNEG]
    const float* __restrict__ z1, const float* __restrict__ z2,
    int rowOffset, float* __restrict__ rowloss)
{
    __shared__ int   hcnt[4096];
    __shared__ int   segc[256];
    __shared__ int   sufc[256];
    __shared__ float fscratch[4];
    __shared__ int   iscratch[4];
    __shared__ int   sel_seg;
    __shared__ int   sh_bt, sh_run;

    const int tid = threadIdx.x;
    const int grow = rowOffset + blockIdx.x;
    const unsigned short* srow = simb + (size_t)blockIdx.x * NNEG;

    #pragma unroll
    for (int j = 0; j < 16; j++) hcnt[tid * 16 + j] = 0;

    // positive similarity (fp32 z); contains syncthreads (also orders hist zeroing)
    float p = z1[(size_t)grow * PROJ + tid] * z2[(size_t)grow * PROJ + tid];
    float pos = blockReduceSumF(p, fscratch);
    __syncthreads();

    // ---- pass 1: count histogram ----
    for (int i = tid * 8; i < NNEG; i += 256 * 8) {
        uint4 v4 = *(const uint4*)(srow + i);
        const unsigned short* u = (const unsigned short*)&v4;
        #pragma unroll
        for (int j = 0; j < 8; j++) {
            float v = b2f(u[j]);
            int k = (int)fmaf(v, 2048.f, 2048.f);
            k = min(max(k, 0), 4095);
            atomicAdd(&hcnt[k], 1);
        }
    }
    __syncthreads();

    // per-segment totals (segment t = bins [16t, 16t+15])
    int c = 0;
    #pragma unroll
    for (int j = 0; j < 16; j++) c += hcnt[tid * 16 + j];
    segc[tid] = c;
    sufc[tid] = c;
    __syncthreads();
    // inclusive suffix scan over segments
    for (int st = 1; st < 256; st <<= 1) {
        int aC = (tid + st < 256) ? sufc[tid + st] : 0;
        __syncthreads();
        sufc[tid] += aC;
        __syncthreads();
    }
    // unique segment containing the K-th largest
    if (sufc[tid] >= TOPK && sufc[tid] - segc[tid] < TOPK) sel_seg = tid;
    __syncthreads();
    if (tid == 0) {
        int t = sel_seg;
        int running = sufc[t] - segc[t];       // count strictly above segment t
        int bt = t * 16;
        for (int j = 15; j >= 0; j--) {
            int b = t * 16 + j;
            int cb = hcnt[b];
            if (running + cb >= TOPK) { bt = b; break; }
            running += cb;
        }
        sh_bt = bt; sh_run = running;
    }
    __syncthreads();
    const int bt = sh_bt;
    const float m = INV_T;

    // ---- pass 2: exp only above/at threshold bucket ----
    float s_above = 0.f, s_eq = 0.f;
    int c_eq = 0;
    for (int i = tid * 8; i < NNEG; i += 256 * 8) {
        uint4 v4 = *(const uint4*)(srow + i);
        const unsigned short* u = (const unsigned short*)&v4;
        #pragma unroll
        for (int j = 0; j < 8; j++) {
            float v = b2f(u[j]);
            int k = (int)fmaf(v, 2048.f, 2048.f);
            k = min(max(k, 0), 4095);
            if (k >= bt) {
                float e = __expf(fmaf(v, INV_T, -m));
                if (k > bt) s_above += e;
                else { s_eq += e; c_eq++; }
            }
        }
    }
    s_above = blockReduceSumF(s_above, fscratch);
    __syncthreads();
    s_eq = blockReduceSumF(s_eq, fscratch);
    c_eq = blockReduceSumI(c_eq, iscratch);
    if (tid == 0) {
        int need = TOPK - sh_run;
        float avg = s_eq / (float)c_eq;
        float total = s_above + (float)need * avg + __expf(fmaf(pos, INV_T, -m));
        rowloss[grow] = m + logf(total) - pos * INV_T;
    }
}

__global__ __launch_bounds__(256) void loss_reduce(const float* __restrict__ rowloss,
                                                   float* __restrict__ out)
{
    __shared__ float scratch[4];
    float s = 0.f;
    for (int i = threadIdx.x; i < BATCH; i += 256) s += rowloss[i];
    s = blockReduceSumF(s, scratch);
    if (threadIdx.x == 0) out[0] = s / (float)BATCH;
}

// ---------- launcher ----------
extern "C" void kernel_launch(void* const* d_in, const int* in_sizes, int n_in,
                              void* d_out, int out_size, void* d_ws, size_t ws_size,
                              hipStream_t stream)
{
    const float* h1    = (const float*)d_in[0];
    const float* h2    = (const float*)d_in[1];
    const float* hneg  = (const float*)d_in[2];
    const float* W1    = (const float*)d_in[3];
    const float* b1    = (const float*)d_in[4];
    const float* gamma = (const float*)d_in[5];
    const float* beta  = (const float*)d_in[6];
    const float* W2    = (const float*)d_in[7];
    const float* b2    = (const float*)d_in[8];
    float* out = (float*)d_out;
    float* ws  = (float*)d_ws;

    // workspace layout (float offsets); total 51,003,392 f = 204 MB
    unsigned short* hneg_b = (unsigned short*)ws;                 // 32768x1024 bf16 = 16,777,216 f
    unsigned short* Yb   = (unsigned short*)(ws + 16777216);      // 40960x1024 bf16 = 20,971,520 f
    unsigned short* Zpre = (unsigned short*)(ws + 37748736);      // 40960x256 bf16  =  5,242,880 f
    unsigned short* Zb   = (unsigned short*)(ws + 42991616);      // 40960x256 bf16  =  5,242,880 f
    float*          Zfp  = ws + 48234496;                         // 8192x256 f32    =  2,097,152 f
    unsigned short* W1b  = (unsigned short*)(ws + 50331648);      // 1M bf16         =    524,288 f
    unsigned short* W2b  = (unsigned short*)(ws + 50855936);      // 256K bf16       =    131,072 f
    float* s_sum   = ws + 50987008;                               // 3*1024 x4
    float* s_sumsq = s_sum + 3072;
    float* s_scale = s_sum + 6144;
    float* s_shift = s_sum + 9216;
    float* rowloss = ws + 50999296;                               // 4096
    unsigned short* simb = hneg_b;                                // overlay (dead after GEMM1-hneg):
                                                                  // CHUNK x NNEG bf16 = 64 MB (exact fit)

    hipMemsetAsync(s_sum, 0, 2 * 3072 * sizeof(float), stream);

    // conversions: weights + h_neg -> bf16
    conv_f2b<<<1024, 256, 0, stream>>>(W1, W1b, HID * HID);
    conv_f2b<<<256, 256, 0, stream>>>(W2, W2b, PROJ * HID);
    conv_f2b8<<<16384, 256, 0, stream>>>(hneg, hneg_b);

    // GEMM1: Yb = bf16(X) @ W1b^T + b1
    {
        dim3 g(HID / BN, BATCH / BM);
        mfma_gemm<1, true><<<g, 256, 0, stream>>>(h1, W1b, b1, Yb, BATCH, HID, HID, nullptr, nullptr);
        mfma_gemm<1, true><<<g, 256, 0, stream>>>(h2, W1b, b1, Yb + (size_t)BATCH * HID,
                                                  BATCH, HID, HID, nullptr, nullptr);
        dim3 gn(HID / BN, NNEG / BM);
        mfma_gemm<0, true><<<gn, 256, 0, stream>>>(hneg_b, W1b, b1, Yb + (size_t)2 * BATCH * HID,
                                                   NNEG, HID, HID, nullptr, nullptr);
    }

    const int rows[3] = { BATCH, BATCH, NNEG };
    const int yoff[3] = { 0, BATCH, 2 * BATCH };

    // BN stats + finalize (scale/shift form)
    for (int s = 0; s < 3; s++) {
        bn_stats<<<rows[s] / 32, 256, 0, stream>>>(Yb + (size_t)yoff[s] * HID, rows[s],
                                                   s_sum + s * HID, s_sumsq + s * HID);
    }
    bn_finalize<<<dim3(HID / 256, 3), 256, 0, stream>>>(s_sum, s_sumsq, gamma, beta, s_scale, s_shift);

    // GEMM2: Zpre = GELU(BN(Yb)) @ W2b^T + b2 (bf16 out)
    for (int s = 0; s < 3; s++) {
        dim3 g(PROJ / BN, rows[s] / BM);
        mfma_gemm<2, true><<<g, 256, 0, stream>>>(Yb + (size_t)yoff[s] * HID, W2b, b2,
                                                  Zpre + (size_t)yoff[s] * PROJ,
                                                  rows[s], PROJ, HID,
                                                  s_scale + s * HID, s_shift + s * HID);
    }
    // L2 normalize
    l2norm<<<ROWS_TOTAL, 256, 0, stream>>>(Zpre, Zb, Zfp);

    // sim chunks (bf16 sim): sim = z1_chunk @ z_neg^T, then two-pass hist top-k loss
    const unsigned short* znegb = Zb + (size_t)(2 * BATCH) * PROJ;
    const float* z2v = Zfp + (size_t)BATCH * PROJ;
    for (int c = 0; c < BATCH / CHUNK; c++) {
        dim3 g(NNEG / BN, CHUNK / BM);
        mfma_gemm<0, true><<<g, 256, 0, stream>>>(Zb + (size_t)(c * CHUNK) * PROJ, znegb, nullptr,
                                                  simb, CHUNK, NNEG, PROJ, nullptr, nullptr);
        topk_loss<<<CHUNK, 256, 0, stream>>>(simb, Zfp, z2v, c * CHUNK, rowloss);
    }
    loss_reduce<<<1, 256, 0, stream>>>(rowloss, out);
}

// Round 6
// 948.219 us; speedup vs baseline: 10.3800x; 1.4564x over previous
//
#include <hip/hip_runtime.h>
#include <hip/hip_bf16.h>
#include <math.h>

#define BATCH 4096
#define NNEG 32768
#define HID 1024
#define PROJ 256
#define TOPK 128
#define ROWS_TOTAL 40960
#define CHUNK 1024
#define INV_T 14.2857142857142857f  // 1/0.07

#define BM 128
#define BN 128
#define BK 64
#define LDK 72   // padded LDS row stride (elements)

#define BNS_ROWS 128   // rows per bn_stats_partial block

typedef __attribute__((ext_vector_type(8))) short bf16x8;
typedef __attribute__((ext_vector_type(4))) float f32x4;

// ---------- helpers ----------
__device__ __forceinline__ float b2f(unsigned short u) {
    return __uint_as_float(((unsigned)u) << 16);
}
__device__ __forceinline__ unsigned short f2b(float f) {
    unsigned u = __float_as_uint(f);
    unsigned r = (u + 0x7FFFu + ((u >> 16) & 1u)) >> 16;  // RNE
    return (unsigned short)r;
}
__device__ __forceinline__ float gelu_exact(float v) {
    return 0.5f * v * (1.0f + erff(v * 0.70710678118654752f));
}

__device__ __forceinline__ float blockReduceSumF(float v, volatile float* scratch) {
    #pragma unroll
    for (int o = 32; o > 0; o >>= 1) v += __shfl_down(v, o);
    int wid = threadIdx.x >> 6, lane = threadIdx.x & 63;
    __syncthreads();
    if (lane == 0) scratch[wid] = v;
    __syncthreads();
    return scratch[0] + scratch[1] + scratch[2] + scratch[3];
}
__device__ __forceinline__ int blockReduceSumI(int v, volatile int* scratch) {
    #pragma unroll
    for (int o = 32; o > 0; o >>= 1) v += __shfl_down(v, o);
    int wid = threadIdx.x >> 6, lane = threadIdx.x & 63;
    __syncthreads();
    if (lane == 0) scratch[wid] = v;
    __syncthreads();
    return scratch[0] + scratch[1] + scratch[2] + scratch[3];
}

// ---------- fp32 -> bf16 conversion ----------
__global__ __launch_bounds__(256) void conv_f2b(const float* __restrict__ src,
                                                unsigned short* __restrict__ dst, int n)
{
    int i = (blockIdx.x * 256 + threadIdx.x) * 4;
    if (i + 3 < n) {
        float4 v = *(const float4*)(src + i);
        ushort4 o;
        o.x = f2b(v.x); o.y = f2b(v.y); o.z = f2b(v.z); o.w = f2b(v.w);
        *(ushort4*)(dst + i) = o;
    }
}

// 8 elems/thread version for the big h_neg conversion
__global__ __launch_bounds__(256) void conv_f2b8(const float* __restrict__ src,
                                                 unsigned short* __restrict__ dst)
{
    int i = (blockIdx.x * 256 + threadIdx.x) * 8;
    float4 a = *(const float4*)(src + i);
    float4 b = *(const float4*)(src + i + 4);
    ushort4 o0, o1;
    o0.x = f2b(a.x); o0.y = f2b(a.y); o0.z = f2b(a.z); o0.w = f2b(a.w);
    o1.x = f2b(b.x); o1.y = f2b(b.y); o1.z = f2b(b.z); o1.w = f2b(b.w);
    *(ushort4*)(dst + i) = o0;
    *(ushort4*)(dst + i + 4) = o1;
}

// ---------- XCD-chunked bijective swizzle (nwg % 8 == 0 in all launches) ----------
__device__ __forceinline__ void xcd_swizzle(int& bx, int& by) {
    int gx = gridDim.x;
    int orig = by * gx + bx;
    int q = (gx * gridDim.y) >> 3;
    int wg = (orig & 7) * q + (orig >> 3);
    bx = wg % gx;
    by = wg / gx;
}

// ---------- MFMA GEMM: C[M,N] = act(A[M,K]) @ Bw[N,K]^T + bias ----------
// AMODE 0: A is bf16 (ushort), copied as-is.
// AMODE 1: A is fp32, converted to bf16 during staging.
// AMODE 2: A is bf16; BN (scale/shift per k) + exact GELU applied, re-converted.
template<int AMODE, bool OUT_BF16>
__global__ __launch_bounds__(256) void mfma_gemm(
    const void* __restrict__ Av, const unsigned short* __restrict__ Bw,
    const float* __restrict__ bias, void* __restrict__ Cv,
    int M, int N, int K,
    const float* __restrict__ bnscale, const float* __restrict__ bnshift)
{
    __shared__ unsigned short As[BM * LDK];
    __shared__ unsigned short Bs[BN * LDK];
    const int tid = threadIdx.x;
    int bxi = blockIdx.x, byi = blockIdx.y;
    xcd_swizzle(bxi, byi);
    const int bm = byi * BM;
    const int bn = bxi * BN;
    const int wave = tid >> 6;
    const int lane = tid & 63;
    const int wm = (wave >> 1) * 64;
    const int wn = (wave & 1) * 64;
    const int fr = lane & 15;   // A-row / B-col / C-col
    const int fg = lane >> 4;   // k-group
    const int srow = tid >> 1;            // staging row 0..127
    const int scol = (tid & 1) * 32;      // staging col base

    f32x4 acc[4][4] = {};

    for (int k0 = 0; k0 < K; k0 += BK) {
        // ---- stage A tile [BM][BK] ----
        if (AMODE == 0) {
            const unsigned short* A = (const unsigned short*)Av;
            const uint4* src = (const uint4*)(A + (size_t)(bm + srow) * K + k0 + scol);
            uint4 v0 = src[0], v1 = src[1], v2 = src[2], v3 = src[3];
            uint4* dst = (uint4*)&As[srow * LDK + scol];
            dst[0] = v0; dst[1] = v1; dst[2] = v2; dst[3] = v3;
        } else if (AMODE == 1) {
            const float* A = (const float*)Av;
            const float* src = A + (size_t)(bm + srow) * K + k0 + scol;
            union { unsigned short us[32]; uint4 u4[4]; } tmp;
            #pragma unroll
            for (int j = 0; j < 32; j += 4) {
                float4 v = *(const float4*)(src + j);
                tmp.us[j+0] = f2b(v.x); tmp.us[j+1] = f2b(v.y);
                tmp.us[j+2] = f2b(v.z); tmp.us[j+3] = f2b(v.w);
            }
            uint4* dst = (uint4*)&As[srow * LDK + scol];
            #pragma unroll
            for (int j = 0; j < 4; j++) dst[j] = tmp.u4[j];
        } else {
            const unsigned short* A = (const unsigned short*)Av;
            const uint4* src = (const uint4*)(A + (size_t)(bm + srow) * K + k0 + scol);
            union { unsigned short us[32]; uint4 u4[4]; } raw, tmp;
            #pragma unroll
            for (int j = 0; j < 4; j++) raw.u4[j] = src[j];
            #pragma unroll
            for (int j = 0; j < 32; j++) {
                int kc = k0 + scol + j;
                float v = b2f(raw.us[j]);
                v = fmaf(v, bnscale[kc], bnshift[kc]);
                tmp.us[j] = f2b(gelu_exact(v));
            }
            uint4* dst = (uint4*)&As[srow * LDK + scol];
            #pragma unroll
            for (int j = 0; j < 4; j++) dst[j] = tmp.u4[j];
        }
        // ---- stage B tile [BN][BK] ----
        {
            const uint4* src = (const uint4*)(Bw + (size_t)(bn + srow) * K + k0 + scol);
            uint4 v0 = src[0], v1 = src[1], v2 = src[2], v3 = src[3];
            uint4* dst = (uint4*)&Bs[srow * LDK + scol];
            dst[0] = v0; dst[1] = v1; dst[2] = v2; dst[3] = v3;
        }
        __syncthreads();
        // ---- MFMA ----
        #pragma unroll
        for (int ks = 0; ks < 2; ks++) {
            bf16x8 a[4], b[4];
            #pragma unroll
            for (int mi = 0; mi < 4; mi++)
                a[mi] = *(const bf16x8*)&As[(wm + mi * 16 + fr) * LDK + ks * 32 + fg * 8];
            #pragma unroll
            for (int ni = 0; ni < 4; ni++)
                b[ni] = *(const bf16x8*)&Bs[(wn + ni * 16 + fr) * LDK + ks * 32 + fg * 8];
            #pragma unroll
            for (int mi = 0; mi < 4; mi++)
                #pragma unroll
                for (int ni = 0; ni < 4; ni++)
                    acc[mi][ni] = __builtin_amdgcn_mfma_f32_16x16x32_bf16(a[mi], b[ni], acc[mi][ni], 0, 0, 0);
        }
        __syncthreads();
    }

    // ---- epilogue: C/D layout col=lane&15, row=(lane>>4)*4+reg ----
    #pragma unroll
    for (int mi = 0; mi < 4; mi++) {
        #pragma unroll
        for (int ni = 0; ni < 4; ni++) {
            int col = bn + wn + ni * 16 + fr;
            int row0 = bm + wm + mi * 16 + fg * 4;
            float bv = bias ? bias[col] : 0.0f;
            #pragma unroll
            for (int r = 0; r < 4; r++) {
                float v = acc[mi][ni][r] + bv;
                if (OUT_BF16) {
                    ((unsigned short*)Cv)[(size_t)(row0 + r) * N + col] = f2b(v);
                } else {
                    ((float*)Cv)[(size_t)(row0 + r) * N + col] = v;
                }
            }
        }
    }
}

// ---------- BN stats, stage 1: per-block partials, atomic-free ----------
// Block = BNS_ROWS rows x 1024 cols. Writes [2][1024] partial floats per block.
__global__ __launch_bounds__(256) void bn_stats_partial(const unsigned short* __restrict__ Yb,
                                                        float* __restrict__ partial)
{
    __shared__ float lsum[1024];
    __shared__ float lssq[1024];
    const int cg = (threadIdx.x & 127) * 8;
    int r = blockIdx.x * BNS_ROWS + (threadIdx.x >> 7);
    float s[8] = {}, ss[8] = {};
    #pragma unroll 4
    for (int i = 0; i < BNS_ROWS / 2; i++, r += 2) {
        uint4 v = *(const uint4*)&Yb[(size_t)r * HID + cg];
        const unsigned short* u = (const unsigned short*)&v;
        #pragma unroll
        for (int j = 0; j < 8; j++) {
            float f = b2f(u[j]);
            s[j] += f; ss[j] += f * f;
        }
    }
    if (threadIdx.x >= 128) {
        #pragma unroll
        for (int j = 0; j < 8; j++) { lsum[cg + j] = s[j]; lssq[cg + j] = ss[j]; }
    }
    __syncthreads();
    if (threadIdx.x < 128) {
        float* outs = partial + (size_t)blockIdx.x * 2048;
        #pragma unroll
        for (int j = 0; j < 8; j++) {
            outs[cg + j]        = s[j] + lsum[cg + j];
            outs[1024 + cg + j] = ss[j] + lssq[cg + j];
        }
    }
}

// ---------- BN stats, stage 2: reduce partials + finalize scale/shift ----------
// grid (HID/256, 3); partial layout: seg0 @ 0 (32 blk), seg1 @ 32*2048, seg2 @ 64*2048 (256 blk)
__global__ __launch_bounds__(256) void bn_reduce_finalize(
    const float* __restrict__ partial,
    const float* __restrict__ gamma, const float* __restrict__ beta,
    float* __restrict__ scale, float* __restrict__ shift)
{
    int seg = blockIdx.y;
    int col = blockIdx.x * 256 + threadIdx.x;
    int base = (seg == 0) ? 0 : (seg == 1) ? 32 : 64;
    int nblk = (seg == 2) ? 256 : 32;
    const float* p = partial + (size_t)base * 2048;
    float s = 0.f, ss = 0.f;
    for (int b = 0; b < nblk; b++) {
        s  += p[(size_t)b * 2048 + col];
        ss += p[(size_t)b * 2048 + 1024 + col];
    }
    float n = (seg == 2) ? (float)NNEG : (float)BATCH;
    float mu = s / n;
    float var = ss / n - mu * mu;
    float sc = gamma[col] * rsqrtf(var + 1e-5f);
    scale[seg * HID + col] = sc;
    shift[seg * HID + col] = beta[col] - mu * sc;
}

// ---------- L2 normalize rows; read bf16 pre-norm, write bf16 all + fp32 first 8192 ----------
__global__ __launch_bounds__(256) void l2norm(const unsigned short* __restrict__ Zpre,
                                              unsigned short* __restrict__ Zb,
                                              float* __restrict__ Zfp)
{
    __shared__ float scratch[4];
    size_t r = blockIdx.x;
    float v = b2f(Zpre[r * PROJ + threadIdx.x]);
    float t = blockReduceSumF(v * v, scratch);
    float scale = 1.0f / fmaxf(sqrtf(t), 1e-12f);
    float o = v * scale;
    Zb[r * PROJ + threadIdx.x] = f2b(o);
    if (r < 2 * BATCH) Zfp[r * PROJ + threadIdx.x] = o;
}

// ---------- two-pass hist top-k loss ----------
__global__ __launch_bounds__(256) void topk_loss(
    const unsigned short* __restrict__ simb,   // [CHUNK x NNEG]
    const float* __restrict__ z1, const float* __restrict__ z2,
    int rowOffset, float* __restrict__ rowloss)
{
    __shared__ int   hcnt[4096];
    __shared__ int   segc[256];
    __shared__ int   sufc[256];
    __shared__ float fscratch[4];
    __shared__ int   iscratch[4];
    __shared__ int   sel_seg;
    __shared__ int   sh_bt, sh_run;

    const int tid = threadIdx.x;
    const int grow = rowOffset + blockIdx.x;
    const unsigned short* srow = simb + (size_t)blockIdx.x * NNEG;

    #pragma unroll
    for (int j = 0; j < 16; j++) hcnt[tid * 16 + j] = 0;

    // positive similarity (fp32 z); contains syncthreads (also orders hist zeroing)
    float p = z1[(size_t)grow * PROJ + tid] * z2[(size_t)grow * PROJ + tid];
    float pos = blockReduceSumF(p, fscratch);
    __syncthreads();

    // ---- pass 1: count histogram ----
    for (int i = tid * 8; i < NNEG; i += 256 * 8) {
        uint4 v4 = *(const uint4*)(srow + i);
        const unsigned short* u = (const unsigned short*)&v4;
        #pragma unroll
        for (int j = 0; j < 8; j++) {
            float v = b2f(u[j]);
            int k = (int)fmaf(v, 2048.f, 2048.f);
            k = min(max(k, 0), 4095);
            atomicAdd(&hcnt[k], 1);
        }
    }
    __syncthreads();

    // per-segment totals (segment t = bins [16t, 16t+15])
    int c = 0;
    #pragma unroll
    for (int j = 0; j < 16; j++) c += hcnt[tid * 16 + j];
    segc[tid] = c;
    sufc[tid] = c;
    __syncthreads();
    // inclusive suffix scan over segments
    for (int st = 1; st < 256; st <<= 1) {
        int aC = (tid + st < 256) ? sufc[tid + st] : 0;
        __syncthreads();
        sufc[tid] += aC;
        __syncthreads();
    }
    // unique segment containing the K-th largest
    if (sufc[tid] >= TOPK && sufc[tid] - segc[tid] < TOPK) sel_seg = tid;
    __syncthreads();
    if (tid == 0) {
        int t = sel_seg;
        int running = sufc[t] - segc[t];       // count strictly above segment t
        int bt = t * 16;
        for (int j = 15; j >= 0; j--) {
            int b = t * 16 + j;
            int cb = hcnt[b];
            if (running + cb >= TOPK) { bt = b; break; }
            running += cb;
        }
        sh_bt = bt; sh_run = running;
    }
    __syncthreads();
    const int bt = sh_bt;
    const float m = INV_T;

    // ---- pass 2: exp only above/at threshold bucket ----
    float s_above = 0.f, s_eq = 0.f;
    int c_eq = 0;
    for (int i = tid * 8; i < NNEG; i += 256 * 8) {
        uint4 v4 = *(const uint4*)(srow + i);
        const unsigned short* u = (const unsigned short*)&v4;
        #pragma unroll
        for (int j = 0; j < 8; j++) {
            float v = b2f(u[j]);
            int k = (int)fmaf(v, 2048.f, 2048.f);
            k = min(max(k, 0), 4095);
            if (k >= bt) {
                float e = __expf(fmaf(v, INV_T, -m));
                if (k > bt) s_above += e;
                else { s_eq += e; c_eq++; }
            }
        }
    }
    s_above = blockReduceSumF(s_above, fscratch);
    __syncthreads();
    s_eq = blockReduceSumF(s_eq, fscratch);
    c_eq = blockReduceSumI(c_eq, iscratch);
    if (tid == 0) {
        int need = TOPK - sh_run;
        float avg = s_eq / (float)c_eq;
        float total = s_above + (float)need * avg + __expf(fmaf(pos, INV_T, -m));
        rowloss[grow] = m + logf(total) - pos * INV_T;
    }
}

__global__ __launch_bounds__(256) void loss_reduce(const float* __restrict__ rowloss,
                                                   float* __restrict__ out)
{
    __shared__ float scratch[4];
    float s = 0.f;
    for (int i = threadIdx.x; i < BATCH; i += 256) s += rowloss[i];
    s = blockReduceSumF(s, scratch);
    if (threadIdx.x == 0) out[0] = s / (float)BATCH;
}

// ---------- launcher ----------
extern "C" void kernel_launch(void* const* d_in, const int* in_sizes, int n_in,
                              void* d_out, int out_size, void* d_ws, size_t ws_size,
                              hipStream_t stream)
{
    const float* h1    = (const float*)d_in[0];
    const float* h2    = (const float*)d_in[1];
    const float* hneg  = (const float*)d_in[2];
    const float* W1    = (const float*)d_in[3];
    const float* b1    = (const float*)d_in[4];
    const float* gamma = (const float*)d_in[5];
    const float* beta  = (const float*)d_in[6];
    const float* W2    = (const float*)d_in[7];
    const float* b2    = (const float*)d_in[8];
    float* out = (float*)d_out;
    float* ws  = (float*)d_ws;

    // workspace layout (float offsets); total 51,652,608 f = 206.6 MB (< R1's proven 209.8 MB)
    unsigned short* hneg_b = (unsigned short*)ws;                 // 32768x1024 bf16 = 16,777,216 f
    unsigned short* Yb   = (unsigned short*)(ws + 16777216);      // 40960x1024 bf16 = 20,971,520 f
    unsigned short* Zpre = (unsigned short*)(ws + 37748736);      // 40960x256 bf16  =  5,242,880 f
    unsigned short* Zb   = (unsigned short*)(ws + 42991616);      // 40960x256 bf16  =  5,242,880 f
    float*          Zfp  = ws + 48234496;                         // 8192x256 f32    =  2,097,152 f
    unsigned short* W1b  = (unsigned short*)(ws + 50331648);      // 1M bf16         =    524,288 f
    unsigned short* W2b  = (unsigned short*)(ws + 50855936);      // 256K bf16       =    131,072 f
    float* partial = ws + 50987008;                               // (32+32+256)*2048 = 655,360 f
    float* s_scale = ws + 51642368;                               // 3*1024
    float* s_shift = ws + 51645440;                               // 3*1024
    float* rowloss = ws + 51648512;                               // 4096
    unsigned short* simb = hneg_b;                                // overlay (dead after GEMM1-hneg)

    // conversions: weights + h_neg -> bf16
    conv_f2b<<<1024, 256, 0, stream>>>(W1, W1b, HID * HID);
    conv_f2b<<<256, 256, 0, stream>>>(W2, W2b, PROJ * HID);
    conv_f2b8<<<16384, 256, 0, stream>>>(hneg, hneg_b);

    // GEMM1: Yb = bf16(X) @ W1b^T + b1
    {
        dim3 g(HID / BN, BATCH / BM);
        mfma_gemm<1, true><<<g, 256, 0, stream>>>(h1, W1b, b1, Yb, BATCH, HID, HID, nullptr, nullptr);
        mfma_gemm<1, true><<<g, 256, 0, stream>>>(h2, W1b, b1, Yb + (size_t)BATCH * HID,
                                                  BATCH, HID, HID, nullptr, nullptr);
        dim3 gn(HID / BN, NNEG / BM);
        mfma_gemm<0, true><<<gn, 256, 0, stream>>>(hneg_b, W1b, b1, Yb + (size_t)2 * BATCH * HID,
                                                   NNEG, HID, HID, nullptr, nullptr);
    }

    const int rows[3] = { BATCH, BATCH, NNEG };
    const int yoff[3] = { 0, BATCH, 2 * BATCH };
    const int poff[3] = { 0, 32, 64 };

    // BN stats: atomic-free partials + fused reduce/finalize
    for (int s = 0; s < 3; s++) {
        bn_stats_partial<<<rows[s] / BNS_ROWS, 256, 0, stream>>>(
            Yb + (size_t)yoff[s] * HID, partial + (size_t)poff[s] * 2048);
    }
    bn_reduce_finalize<<<dim3(HID / 256, 3), 256, 0, stream>>>(partial, gamma, beta, s_scale, s_shift);

    // GEMM2: Zpre = GELU(BN(Yb)) @ W2b^T + b2 (bf16 out)
    for (int s = 0; s < 3; s++) {
        dim3 g(PROJ / BN, rows[s] / BM);
        mfma_gemm<2, true><<<g, 256, 0, stream>>>(Yb + (size_t)yoff[s] * HID, W2b, b2,
                                                  Zpre + (size_t)yoff[s] * PROJ,
                                                  rows[s], PROJ, HID,
                                                  s_scale + s * HID, s_shift + s * HID);
    }
    // L2 normalize
    l2norm<<<ROWS_TOTAL, 256, 0, stream>>>(Zpre, Zb, Zfp);

    // sim chunks (bf16 sim): sim = z1_chunk @ z_neg^T, then two-pass hist top-k loss
    const unsigned short* znegb = Zb + (size_t)(2 * BATCH) * PROJ;
    const float* z2v = Zfp + (size_t)BATCH * PROJ;
    for (int c = 0; c < BATCH / CHUNK; c++) {
        dim3 g(NNEG / BN, CHUNK / BM);
        mfma_gemm<0, true><<<g, 256, 0, stream>>>(Zb + (size_t)(c * CHUNK) * PROJ, znegb, nullptr,
                                                  simb, CHUNK, NNEG, PROJ, nullptr, nullptr);
        topk_loss<<<CHUNK, 256, 0, stream>>>(simb, Zfp, z2v, c * CHUNK, rowloss);
    }
    loss_reduce<<<1, 256, 0, stream>>>(rowloss, out);
}

// Round 7
// 806.683 us; speedup vs baseline: 12.2012x; 1.1755x over previous
//
#include <hip/hip_runtime.h>
#include <hip/hip_bf16.h>
#include <math.h>

#define BATCH 4096
#define NNEG 32768
#define HID 1024
#define PROJ 256
#define TOPK 128
#define ROWS_TOTAL 40960
#define CHUNK 1024
#define INV_T 14.2857142857142857f  // 1/0.07

#define BM 128
#define BN 128
#define BK 64
#define LDK 72   // padded LDS row stride (elements)

#define BNS_ROWS 128   // rows per bn_stats_partial block

typedef __attribute__((ext_vector_type(8))) short bf16x8;
typedef __attribute__((ext_vector_type(4))) float f32x4;

// ---------- helpers ----------
__device__ __forceinline__ float b2f(unsigned short u) {
    return __uint_as_float(((unsigned)u) << 16);
}
__device__ __forceinline__ unsigned short f2b(float f) {
    unsigned u = __float_as_uint(f);
    unsigned r = (u + 0x7FFFu + ((u >> 16) & 1u)) >> 16;  // RNE
    return (unsigned short)r;
}
__device__ __forceinline__ float gelu_exact(float v) {
    return 0.5f * v * (1.0f + erff(v * 0.70710678118654752f));
}

__device__ __forceinline__ float blockReduceSumF(float v, volatile float* scratch) {
    #pragma unroll
    for (int o = 32; o > 0; o >>= 1) v += __shfl_down(v, o);
    int wid = threadIdx.x >> 6, lane = threadIdx.x & 63;
    __syncthreads();
    if (lane == 0) scratch[wid] = v;
    __syncthreads();
    return scratch[0] + scratch[1] + scratch[2] + scratch[3];
}
__device__ __forceinline__ int blockReduceSumI(int v, volatile int* scratch) {
    #pragma unroll
    for (int o = 32; o > 0; o >>= 1) v += __shfl_down(v, o);
    int wid = threadIdx.x >> 6, lane = threadIdx.x & 63;
    __syncthreads();
    if (lane == 0) scratch[wid] = v;
    __syncthreads();
    return scratch[0] + scratch[1] + scratch[2] + scratch[3];
}

// ---------- fp32 -> bf16 conversion ----------
__global__ __launch_bounds__(256) void conv_f2b(const float* __restrict__ src,
                                                unsigned short* __restrict__ dst, int n)
{
    int i = (blockIdx.x * 256 + threadIdx.x) * 4;
    if (i + 3 < n) {
        float4 v = *(const float4*)(src + i);
        ushort4 o;
        o.x = f2b(v.x); o.y = f2b(v.y); o.z = f2b(v.z); o.w = f2b(v.w);
        *(ushort4*)(dst + i) = o;
    }
}

// 8 elems/thread version for big conversions
__global__ __launch_bounds__(256) void conv_f2b8(const float* __restrict__ src,
                                                 unsigned short* __restrict__ dst)
{
    int i = (blockIdx.x * 256 + threadIdx.x) * 8;
    float4 a = *(const float4*)(src + i);
    float4 b = *(const float4*)(src + i + 4);
    ushort4 o0, o1;
    o0.x = f2b(a.x); o0.y = f2b(a.y); o0.z = f2b(a.z); o0.w = f2b(a.w);
    o1.x = f2b(b.x); o1.y = f2b(b.y); o1.z = f2b(b.z); o1.w = f2b(b.w);
    *(ushort4*)(dst + i) = o0;
    *(ushort4*)(dst + i + 4) = o1;
}

// ---------- XCD-chunked bijective swizzle (nwg % 8 == 0 in all launches) ----------
__device__ __forceinline__ void xcd_swizzle(int& bx, int& by) {
    int gx = gridDim.x;
    int orig = by * gx + bx;
    int q = (gx * gridDim.y) >> 3;
    int wg = (orig & 7) * q + (orig >> 3);
    bx = wg % gx;
    by = wg / gx;
}

// ---------- MFMA GEMM: C[M,N] = A[M,K] @ Bw[N,K]^T + bias ----------
// AMODE 0: A is bf16 (ushort), copied as-is.
// AMODE 1: A is fp32, converted to bf16 during staging.
template<int AMODE, bool OUT_BF16>
__global__ __launch_bounds__(256) void mfma_gemm(
    const void* __restrict__ Av, const unsigned short* __restrict__ Bw,
    const float* __restrict__ bias, void* __restrict__ Cv,
    int M, int N, int K)
{
    __shared__ unsigned short As[BM * LDK];
    __shared__ unsigned short Bs[BN * LDK];
    const int tid = threadIdx.x;
    int bxi = blockIdx.x, byi = blockIdx.y;
    xcd_swizzle(bxi, byi);
    const int bm = byi * BM;
    const int bn = bxi * BN;
    const int wave = tid >> 6;
    const int lane = tid & 63;
    const int wm = (wave >> 1) * 64;
    const int wn = (wave & 1) * 64;
    const int fr = lane & 15;   // A-row / B-col / C-col
    const int fg = lane >> 4;   // k-group
    const int srow = tid >> 1;            // staging row 0..127
    const int scol = (tid & 1) * 32;      // staging col base

    f32x4 acc[4][4] = {};

    for (int k0 = 0; k0 < K; k0 += BK) {
        // ---- stage A tile [BM][BK] ----
        if (AMODE == 0) {
            const unsigned short* A = (const unsigned short*)Av;
            const uint4* src = (const uint4*)(A + (size_t)(bm + srow) * K + k0 + scol);
            uint4 v0 = src[0], v1 = src[1], v2 = src[2], v3 = src[3];
            uint4* dst = (uint4*)&As[srow * LDK + scol];
            dst[0] = v0; dst[1] = v1; dst[2] = v2; dst[3] = v3;
        } else {
            const float* A = (const float*)Av;
            const float* src = A + (size_t)(bm + srow) * K + k0 + scol;
            union { unsigned short us[32]; uint4 u4[4]; } tmp;
            #pragma unroll
            for (int j = 0; j < 32; j += 4) {
                float4 v = *(const float4*)(src + j);
                tmp.us[j+0] = f2b(v.x); tmp.us[j+1] = f2b(v.y);
                tmp.us[j+2] = f2b(v.z); tmp.us[j+3] = f2b(v.w);
            }
            uint4* dst = (uint4*)&As[srow * LDK + scol];
            #pragma unroll
            for (int j = 0; j < 4; j++) dst[j] = tmp.u4[j];
        }
        // ---- stage B tile [BN][BK] ----
        {
            const uint4* src = (const uint4*)(Bw + (size_t)(bn + srow) * K + k0 + scol);
            uint4 v0 = src[0], v1 = src[1], v2 = src[2], v3 = src[3];
            uint4* dst = (uint4*)&Bs[srow * LDK + scol];
            dst[0] = v0; dst[1] = v1; dst[2] = v2; dst[3] = v3;
        }
        __syncthreads();
        // ---- MFMA ----
        #pragma unroll
        for (int ks = 0; ks < 2; ks++) {
            bf16x8 a[4], b[4];
            #pragma unroll
            for (int mi = 0; mi < 4; mi++)
                a[mi] = *(const bf16x8*)&As[(wm + mi * 16 + fr) * LDK + ks * 32 + fg * 8];
            #pragma unroll
            for (int ni = 0; ni < 4; ni++)
                b[ni] = *(const bf16x8*)&Bs[(wn + ni * 16 + fr) * LDK + ks * 32 + fg * 8];
            #pragma unroll
            for (int mi = 0; mi < 4; mi++)
                #pragma unroll
                for (int ni = 0; ni < 4; ni++)
                    acc[mi][ni] = __builtin_amdgcn_mfma_f32_16x16x32_bf16(a[mi], b[ni], acc[mi][ni], 0, 0, 0);
        }
        __syncthreads();
    }

    // ---- epilogue: C/D layout col=lane&15, row=(lane>>4)*4+reg ----
    #pragma unroll
    for (int mi = 0; mi < 4; mi++) {
        #pragma unroll
        for (int ni = 0; ni < 4; ni++) {
            int col = bn + wn + ni * 16 + fr;
            int row0 = bm + wm + mi * 16 + fg * 4;
            float bv = bias ? bias[col] : 0.0f;
            #pragma unroll
            for (int r = 0; r < 4; r++) {
                float v = acc[mi][ni][r] + bv;
                if (OUT_BF16) {
                    ((unsigned short*)Cv)[(size_t)(row0 + r) * N + col] = f2b(v);
                } else {
                    ((float*)Cv)[(size_t)(row0 + r) * N + col] = v;
                }
            }
        }
    }
}

// ---------- BN stats, stage 1: per-block partials, atomic-free ----------
__global__ __launch_bounds__(256) void bn_stats_partial(const unsigned short* __restrict__ Yb,
                                                        float* __restrict__ partial)
{
    __shared__ float lsum[1024];
    __shared__ float lssq[1024];
    const int cg = (threadIdx.x & 127) * 8;
    int r = blockIdx.x * BNS_ROWS + (threadIdx.x >> 7);
    float s[8] = {}, ss[8] = {};
    #pragma unroll 4
    for (int i = 0; i < BNS_ROWS / 2; i++, r += 2) {
        uint4 v = *(const uint4*)&Yb[(size_t)r * HID + cg];
        const unsigned short* u = (const unsigned short*)&v;
        #pragma unroll
        for (int j = 0; j < 8; j++) {
            float f = b2f(u[j]);
            s[j] += f; ss[j] += f * f;
        }
    }
    if (threadIdx.x >= 128) {
        #pragma unroll
        for (int j = 0; j < 8; j++) { lsum[cg + j] = s[j]; lssq[cg + j] = ss[j]; }
    }
    __syncthreads();
    if (threadIdx.x < 128) {
        float* outs = partial + (size_t)blockIdx.x * 2048;
        #pragma unroll
        for (int j = 0; j < 8; j++) {
            outs[cg + j]        = s[j] + lsum[cg + j];
            outs[1024 + cg + j] = ss[j] + lssq[cg + j];
        }
    }
}

// ---------- BN stats, stage 2: reduce partials + finalize scale/shift ----------
__global__ __launch_bounds__(256) void bn_reduce_finalize(
    const float* __restrict__ partial,
    const float* __restrict__ gamma, const float* __restrict__ beta,
    float* __restrict__ scale, float* __restrict__ shift)
{
    int seg = blockIdx.y;
    int col = blockIdx.x * 256 + threadIdx.x;
    int base = (seg == 0) ? 0 : (seg == 1) ? 32 : 64;
    int nblk = (seg == 2) ? 256 : 32;
    const float* p = partial + (size_t)base * 2048;
    float s = 0.f, ss = 0.f;
    for (int b = 0; b < nblk; b++) {
        s  += p[(size_t)b * 2048 + col];
        ss += p[(size_t)b * 2048 + 1024 + col];
    }
    float n = (seg == 2) ? (float)NNEG : (float)BATCH;
    float mu = s / n;
    float var = ss / n - mu * mu;
    float sc = gamma[col] * rsqrtf(var + 1e-5f);
    scale[seg * HID + col] = sc;
    shift[seg * HID + col] = beta[col] - mu * sc;
}

// ---------- in-place BN+GELU over Yb (all ROWS_TOTAL rows) ----------
__global__ __launch_bounds__(256) void bngelu(unsigned short* __restrict__ Yb,
                                              const float* __restrict__ scale,
                                              const float* __restrict__ shift)
{
    size_t i = ((size_t)blockIdx.x * 256 + threadIdx.x) * 8;
    int row = (int)(i >> 10);
    int seg = (row < BATCH) ? 0 : (row < 2 * BATCH) ? 1 : 2;
    int col = (int)(i & 1023);
    const float* sc = scale + seg * HID + col;
    const float* sh = shift + seg * HID + col;
    uint4 v = *(uint4*)&Yb[i];
    unsigned short* u = (unsigned short*)&v;
    #pragma unroll
    for (int j = 0; j < 8; j++) {
        float f = b2f(u[j]);
        f = fmaf(f, sc[j], sh[j]);
        u[j] = f2b(gelu_exact(f));
    }
    *(uint4*)&Yb[i] = v;
}

// ---------- L2 normalize rows; read bf16 pre-norm, write bf16 all + fp32 first 8192 ----------
__global__ __launch_bounds__(256) void l2norm(const unsigned short* __restrict__ Zpre,
                                              unsigned short* __restrict__ Zb,
                                              float* __restrict__ Zfp)
{
    __shared__ float scratch[4];
    size_t r = blockIdx.x;
    float v = b2f(Zpre[r * PROJ + threadIdx.x]);
    float t = blockReduceSumF(v * v, scratch);
    float scale = 1.0f / fmaxf(sqrtf(t), 1e-12f);
    float o = v * scale;
    Zb[r * PROJ + threadIdx.x] = f2b(o);
    if (r < 2 * BATCH) Zfp[r * PROJ + threadIdx.x] = o;
}

// ---------- two-pass hist top-k loss ----------
__global__ __launch_bounds__(256) void topk_loss(
    const unsigned short* __restrict__ simb,   // [CHUNK x NNEG]
    const float* __restrict__ z1, const float* __restrict__ z2,
    int rowOffset, float* __restrict__ rowloss)
{
    __shared__ int   hcnt[4096];
    __shared__ int   segc[256];
    __shared__ int   sufc[256];
    __shared__ float fscratch[4];
    __shared__ int   iscratch[4];
    __shared__ int   sel_seg;
    __shared__ int   sh_bt, sh_run;

    const int tid = threadIdx.x;
    const int grow = rowOffset + blockIdx.x;
    const unsigned short* srow = simb + (size_t)blockIdx.x * NNEG;

    #pragma unroll
    for (int j = 0; j < 16; j++) hcnt[tid * 16 + j] = 0;

    float p = z1[(size_t)grow * PROJ + tid] * z2[(size_t)grow * PROJ + tid];
    float pos = blockReduceSumF(p, fscratch);
    __syncthreads();

    // ---- pass 1: count histogram ----
    for (int i = tid * 8; i < NNEG; i += 256 * 8) {
        uint4 v4 = *(const uint4*)(srow + i);
        const unsigned short* u = (const unsigned short*)&v4;
        #pragma unroll
        for (int j = 0; j < 8; j++) {
            float v = b2f(u[j]);
            int k = (int)fmaf(v, 2048.f, 2048.f);
            k = min(max(k, 0), 4095);
            atomicAdd(&hcnt[k], 1);
        }
    }
    __syncthreads();

    int c = 0;
    #pragma unroll
    for (int j = 0; j < 16; j++) c += hcnt[tid * 16 + j];
    segc[tid] = c;
    sufc[tid] = c;
    __syncthreads();
    for (int st = 1; st < 256; st <<= 1) {
        int aC = (tid + st < 256) ? sufc[tid + st] : 0;
        __syncthreads();
        sufc[tid] += aC;
        __syncthreads();
    }
    if (sufc[tid] >= TOPK && sufc[tid] - segc[tid] < TOPK) sel_seg = tid;
    __syncthreads();
    if (tid == 0) {
        int t = sel_seg;
        int running = sufc[t] - segc[t];
        int bt = t * 16;
        for (int j = 15; j >= 0; j--) {
            int b = t * 16 + j;
            int cb = hcnt[b];
            if (running + cb >= TOPK) { bt = b; break; }
            running += cb;
        }
        sh_bt = bt; sh_run = running;
    }
    __syncthreads();
    const int bt = sh_bt;
    const float m = INV_T;

    // ---- pass 2: exp only above/at threshold bucket ----
    float s_above = 0.f, s_eq = 0.f;
    int c_eq = 0;
    for (int i = tid * 8; i < NNEG; i += 256 * 8) {
        uint4 v4 = *(const uint4*)(srow + i);
        const unsigned short* u = (const unsigned short*)&v4;
        #pragma unroll
        for (int j = 0; j < 8; j++) {
            float v = b2f(u[j]);
            int k = (int)fmaf(v, 2048.f, 2048.f);
            k = min(max(k, 0), 4095);
            if (k >= bt) {
                float e = __expf(fmaf(v, INV_T, -m));
                if (k > bt) s_above += e;
                else { s_eq += e; c_eq++; }
            }
        }
    }
    s_above = blockReduceSumF(s_above, fscratch);
    __syncthreads();
    s_eq = blockReduceSumF(s_eq, fscratch);
    c_eq = blockReduceSumI(c_eq, iscratch);
    if (tid == 0) {
        int need = TOPK - sh_run;
        float avg = s_eq / (float)c_eq;
        float total = s_above + (float)need * avg + __expf(fmaf(pos, INV_T, -m));
        rowloss[grow] = m + logf(total) - pos * INV_T;
    }
}

__global__ __launch_bounds__(256) void loss_reduce(const float* __restrict__ rowloss,
                                                   float* __restrict__ out)
{
    __shared__ float scratch[4];
    float s = 0.f;
    for (int i = threadIdx.x; i < BATCH; i += 256) s += rowloss[i];
    s = blockReduceSumF(s, scratch);
    if (threadIdx.x == 0) out[0] = s / (float)BATCH;
}

// ---------- launcher ----------
extern "C" void kernel_launch(void* const* d_in, const int* in_sizes, int n_in,
                              void* d_out, int out_size, void* d_ws, size_t ws_size,
                              hipStream_t stream)
{
    const float* h1    = (const float*)d_in[0];
    const float* h2    = (const float*)d_in[1];
    const float* hneg  = (const float*)d_in[2];
    const float* W1    = (const float*)d_in[3];
    const float* b1    = (const float*)d_in[4];
    const float* gamma = (const float*)d_in[5];
    const float* beta  = (const float*)d_in[6];
    const float* W2    = (const float*)d_in[7];
    const float* b2    = (const float*)d_in[8];
    float* out = (float*)d_out;
    float* ws  = (float*)d_ws;

    // workspace layout (float offsets); total 51,652,608 f = 206.6 MB
    unsigned short* hneg_b = (unsigned short*)ws;                 // 32768x1024 bf16 = 16,777,216 f
    unsigned short* Yb   = (unsigned short*)(ws + 16777216);      // 40960x1024 bf16 = 20,971,520 f
    unsigned short* Zpre = (unsigned short*)(ws + 37748736);      // 40960x256 bf16  =  5,242,880 f
    unsigned short* Zb   = (unsigned short*)(ws + 42991616);      // 40960x256 bf16  =  5,242,880 f
    float*          Zfp  = ws + 48234496;                         // 8192x256 f32    =  2,097,152 f
    unsigned short* W1b  = (unsigned short*)(ws + 50331648);      // 1M bf16         =    524,288 f
    unsigned short* W2b  = (unsigned short*)(ws + 50855936);      // 256K bf16       =    131,072 f
    float* partial = ws + 50987008;                               // (32+32+256)*2048 = 655,360 f
    float* s_scale = ws + 51642368;                               // 3*1024
    float* s_shift = ws + 51645440;                               // 3*1024
    float* rowloss = ws + 51648512;                               // 4096
    unsigned short* simb = hneg_b;                                // overlay (dead after GEMM1-hneg)
    unsigned short* h12b = Zb;                                    // overlay Zb (dead until l2norm):
                                                                  // 8192x1024 bf16 = 16.8 MB < 21 MB

    // conversions: weights + h_neg + h1/h2 -> bf16
    conv_f2b<<<1024, 256, 0, stream>>>(W1, W1b, HID * HID);
    conv_f2b<<<256, 256, 0, stream>>>(W2, W2b, PROJ * HID);
    conv_f2b8<<<16384, 256, 0, stream>>>(hneg, hneg_b);
    conv_f2b8<<<2048, 256, 0, stream>>>(h1, h12b);
    conv_f2b8<<<2048, 256, 0, stream>>>(h2, h12b + (size_t)BATCH * HID);

    // GEMM1: Yb = X_b @ W1b^T + b1 (all AMODE 0)
    {
        dim3 g(HID / BN, 2 * BATCH / BM);
        mfma_gemm<0, true><<<g, 256, 0, stream>>>(h12b, W1b, b1, Yb, 2 * BATCH, HID, HID);
        dim3 gn(HID / BN, NNEG / BM);
        mfma_gemm<0, true><<<gn, 256, 0, stream>>>(hneg_b, W1b, b1, Yb + (size_t)2 * BATCH * HID,
                                                   NNEG, HID, HID);
    }

    const int rows[3] = { BATCH, BATCH, NNEG };
    const int yoff[3] = { 0, BATCH, 2 * BATCH };
    const int poff[3] = { 0, 32, 64 };

    // BN stats: atomic-free partials + fused reduce/finalize
    for (int s = 0; s < 3; s++) {
        bn_stats_partial<<<rows[s] / BNS_ROWS, 256, 0, stream>>>(
            Yb + (size_t)yoff[s] * HID, partial + (size_t)poff[s] * 2048);
    }
    bn_reduce_finalize<<<dim3(HID / 256, 3), 256, 0, stream>>>(partial, gamma, beta, s_scale, s_shift);

    // in-place BN+GELU on Yb (memory-bound, full occupancy)
    bngelu<<<ROWS_TOTAL * HID / 8 / 256, 256, 0, stream>>>(Yb, s_scale, s_shift);

    // GEMM2: Zpre = Yb @ W2b^T + b2 (AMODE 0, bf16 out)
    for (int s = 0; s < 3; s++) {
        dim3 g(PROJ / BN, rows[s] / BM);
        mfma_gemm<0, true><<<g, 256, 0, stream>>>(Yb + (size_t)yoff[s] * HID, W2b, b2,
                                                  Zpre + (size_t)yoff[s] * PROJ,
                                                  rows[s], PROJ, HID);
    }
    // L2 normalize (writes Zb — h12b overlay is dead by now)
    l2norm<<<ROWS_TOTAL, 256, 0, stream>>>(Zpre, Zb, Zfp);

    // sim chunks (bf16 sim): sim = z1_chunk @ z_neg^T, then two-pass hist top-k loss
    const unsigned short* znegb = Zb + (size_t)(2 * BATCH) * PROJ;
    const float* z2v = Zfp + (size_t)BATCH * PROJ;
    for (int c = 0; c < BATCH / CHUNK; c++) {
        dim3 g(NNEG / BN, CHUNK / BM);
        mfma_gemm<0, true><<<g, 256, 0, stream>>>(Zb + (size_t)(c * CHUNK) * PROJ, znegb, nullptr,
                                                  simb, CHUNK, NNEG, PROJ);
        topk_loss<<<CHUNK, 256, 0, stream>>>(simb, Zfp, z2v, c * CHUNK, rowloss);
    }
    loss_reduce<<<1, 256, 0, stream>>>(rowloss, out);
}

// Round 8
// 669.941 us; speedup vs baseline: 14.6916x; 1.2041x over previous
//
#include <hip/hip_runtime.h>
#include <hip/hip_bf16.h>
#include <math.h>

#define BATCH 4096
#define NNEG 32768
#define HID 1024
#define PROJ 256
#define TOPK 128
#define ROWS_TOTAL 40960
#define CHUNK 1024
#define INV_T 14.2857142857142857f  // 1/0.07

#define BM 128
#define BN 128
#define BK 64

#define BNS_ROWS 128   // rows per bn_stats_partial block

typedef __attribute__((ext_vector_type(8))) short bf16x8;
typedef __attribute__((ext_vector_type(4))) float f32x4;

// ---------- helpers ----------
__device__ __forceinline__ float b2f(unsigned short u) {
    return __uint_as_float(((unsigned)u) << 16);
}
__device__ __forceinline__ unsigned short f2b(float f) {
    unsigned u = __float_as_uint(f);
    unsigned r = (u + 0x7FFFu + ((u >> 16) & 1u)) >> 16;  // RNE
    return (unsigned short)r;
}
// branchless tanh-GELU: v * sigmoid(1.5957691(v + 0.044715 v^3)), exp2 form
__device__ __forceinline__ float gelu_fast(float v) {
    float v2 = v * v;
    float w = v * fmaf(v2, -0.1029433f, -2.3022086f);
    float e = exp2f(w);
    return v * __builtin_amdgcn_rcpf(1.0f + e);
}

__device__ __forceinline__ float blockReduceSumF(float v, volatile float* scratch) {
    #pragma unroll
    for (int o = 32; o > 0; o >>= 1) v += __shfl_down(v, o);
    int wid = threadIdx.x >> 6, lane = threadIdx.x & 63;
    __syncthreads();
    if (lane == 0) scratch[wid] = v;
    __syncthreads();
    return scratch[0] + scratch[1] + scratch[2] + scratch[3];
}
__device__ __forceinline__ int blockReduceSumI(int v, volatile int* scratch) {
    #pragma unroll
    for (int o = 32; o > 0; o >>= 1) v += __shfl_down(v, o);
    int wid = threadIdx.x >> 6, lane = threadIdx.x & 63;
    __syncthreads();
    if (lane == 0) scratch[wid] = v;
    __syncthreads();
    return scratch[0] + scratch[1] + scratch[2] + scratch[3];
}

// async global->LDS, 16B per lane; lds base must be wave-uniform
__device__ __forceinline__ void gl_lds16(const unsigned short* g, unsigned short* l) {
    __builtin_amdgcn_global_load_lds(
        (const __attribute__((address_space(1))) unsigned*)g,
        (__attribute__((address_space(3))) unsigned*)l, 16, 0, 0);
}

// ---------- fp32 -> bf16 conversion ----------
__global__ __launch_bounds__(256) void conv_f2b(const float* __restrict__ src,
                                                unsigned short* __restrict__ dst, int n)
{
    int i = (blockIdx.x * 256 + threadIdx.x) * 4;
    if (i + 3 < n) {
        float4 v = *(const float4*)(src + i);
        ushort4 o;
        o.x = f2b(v.x); o.y = f2b(v.y); o.z = f2b(v.z); o.w = f2b(v.w);
        *(ushort4*)(dst + i) = o;
    }
}

__global__ __launch_bounds__(256) void conv_f2b8(const float* __restrict__ src,
                                                 unsigned short* __restrict__ dst)
{
    int i = (blockIdx.x * 256 + threadIdx.x) * 8;
    float4 a = *(const float4*)(src + i);
    float4 b = *(const float4*)(src + i + 4);
    ushort4 o0, o1;
    o0.x = f2b(a.x); o0.y = f2b(a.y); o0.z = f2b(a.z); o0.w = f2b(a.w);
    o1.x = f2b(b.x); o1.y = f2b(b.y); o1.z = f2b(b.z); o1.w = f2b(b.w);
    *(ushort4*)(dst + i) = o0;
    *(ushort4*)(dst + i + 4) = o1;
}

// ---------- XCD-chunked bijective swizzle (nwg % 8 == 0 in all launches) ----------
__device__ __forceinline__ void xcd_swizzle(int& bx, int& by) {
    int gx = gridDim.x;
    int orig = by * gx + bx;
    int q = (gx * gridDim.y) >> 3;
    int wg = (orig & 7) * q + (orig >> 3);
    bx = wg % gx;
    by = wg / gx;
}

// ---------- MFMA GEMM: C[M,N] = A[M,K] @ Bw[N,K]^T (+bias), bf16 in/out ----------
// global_load_lds staging, linear LDS dest + inverse-swizzled source + swizzled read.
// 16B slot p: row = p>>3, stored logical col16 = (p&7)^(row&7).
__global__ __launch_bounds__(256) void mfma_gemm(
    const unsigned short* __restrict__ A, const unsigned short* __restrict__ Bw,
    const float* __restrict__ bias, unsigned short* __restrict__ C,
    int M, int N, int K)
{
    __shared__ unsigned short As[BM * BK];
    __shared__ unsigned short Bs[BN * BK];
    const int tid = threadIdx.x;
    int bxi = blockIdx.x, byi = blockIdx.y;
    xcd_swizzle(bxi, byi);
    const int bm = byi * BM;
    const int bn = bxi * BN;
    const int wave = tid >> 6;
    const int lane = tid & 63;
    const int wm = (wave >> 1) * 64;
    const int wn = (wave & 1) * 64;
    const int fr = lane & 15;   // fragment row (A-row / B-col)
    const int fg = lane >> 4;   // k-group

    // staging slot geometry (per issue i: 64 slots of 16B per wave)
    int s_slot[4], s_row[4], s_c16[4];
    #pragma unroll
    for (int i = 0; i < 4; i++) {
        int s = wave * 256 + i * 64 + lane;
        s_slot[i] = (wave * 256 + i * 64) * 8;   // wave-uniform LDS base (ushort idx)
        s_row[i] = s >> 3;
        s_c16[i] = (s & 7) ^ ((s >> 3) & 7);
    }

    f32x4 acc[4][4] = {};

    for (int k0 = 0; k0 < K; k0 += BK) {
        #pragma unroll
        for (int i = 0; i < 4; i++) {
            gl_lds16(A  + (size_t)(bm + s_row[i]) * K + k0 + s_c16[i] * 8, &As[s_slot[i]]);
            gl_lds16(Bw + (size_t)(bn + s_row[i]) * K + k0 + s_c16[i] * 8, &Bs[s_slot[i]]);
        }
        __syncthreads();
        #pragma unroll
        for (int ks = 0; ks < 2; ks++) {
            bf16x8 a[4], b[4];
            #pragma unroll
            for (int mi = 0; mi < 4; mi++) {
                int row = wm + mi * 16 + fr;
                a[mi] = *(const bf16x8*)&As[row * 64 + (((ks * 4 + fg) ^ (row & 7)) << 3)];
            }
            #pragma unroll
            for (int ni = 0; ni < 4; ni++) {
                int row = wn + ni * 16 + fr;
                b[ni] = *(const bf16x8*)&Bs[row * 64 + (((ks * 4 + fg) ^ (row & 7)) << 3)];
            }
            #pragma unroll
            for (int mi = 0; mi < 4; mi++)
                #pragma unroll
                for (int ni = 0; ni < 4; ni++)
                    acc[mi][ni] = __builtin_amdgcn_mfma_f32_16x16x32_bf16(a[mi], b[ni], acc[mi][ni], 0, 0, 0);
        }
        __syncthreads();
    }

    // epilogue: C/D layout col=lane&15, row=(lane>>4)*4+reg
    #pragma unroll
    for (int mi = 0; mi < 4; mi++) {
        #pragma unroll
        for (int ni = 0; ni < 4; ni++) {
            int col = bn + wn + ni * 16 + fr;
            int row0 = bm + wm + mi * 16 + fg * 4;
            float bv = bias ? bias[col] : 0.0f;
            #pragma unroll
            for (int r = 0; r < 4; r++) {
                float v = acc[mi][ni][r] + bv;
                C[(size_t)(row0 + r) * N + col] = f2b(v);
            }
        }
    }
}

// ---------- BN stats, stage 1: per-block partials, atomic-free ----------
__global__ __launch_bounds__(256) void bn_stats_partial(const unsigned short* __restrict__ Yb,
                                                        float* __restrict__ partial)
{
    __shared__ float lsum[1024];
    __shared__ float lssq[1024];
    const int cg = (threadIdx.x & 127) * 8;
    int r = blockIdx.x * BNS_ROWS + (threadIdx.x >> 7);
    float s[8] = {}, ss[8] = {};
    #pragma unroll 4
    for (int i = 0; i < BNS_ROWS / 2; i++, r += 2) {
        uint4 v = *(const uint4*)&Yb[(size_t)r * HID + cg];
        const unsigned short* u = (const unsigned short*)&v;
        #pragma unroll
        for (int j = 0; j < 8; j++) {
            float f = b2f(u[j]);
            s[j] += f; ss[j] += f * f;
        }
    }
    if (threadIdx.x >= 128) {
        #pragma unroll
        for (int j = 0; j < 8; j++) { lsum[cg + j] = s[j]; lssq[cg + j] = ss[j]; }
    }
    __syncthreads();
    if (threadIdx.x < 128) {
        float* outs = partial + (size_t)blockIdx.x * 2048;
        #pragma unroll
        for (int j = 0; j < 8; j++) {
            outs[cg + j]        = s[j] + lsum[cg + j];
            outs[1024 + cg + j] = ss[j] + lssq[cg + j];
        }
    }
}

// ---------- BN stats, stage 2: reduce partials + finalize scale/shift ----------
__global__ __launch_bounds__(256) void bn_reduce_finalize(
    const float* __restrict__ partial,
    const float* __restrict__ gamma, const float* __restrict__ beta,
    float* __restrict__ scale, float* __restrict__ shift)
{
    int seg = blockIdx.y;
    int col = blockIdx.x * 256 + threadIdx.x;
    int base = (seg == 0) ? 0 : (seg == 1) ? 32 : 64;
    int nblk = (seg == 2) ? 256 : 32;
    const float* p = partial + (size_t)base * 2048;
    float s = 0.f, ss = 0.f;
    for (int b = 0; b < nblk; b++) {
        s  += p[(size_t)b * 2048 + col];
        ss += p[(size_t)b * 2048 + 1024 + col];
    }
    float n = (seg == 2) ? (float)NNEG : (float)BATCH;
    float mu = s / n;
    float var = ss / n - mu * mu;
    float sc = gamma[col] * rsqrtf(var + 1e-5f);
    scale[seg * HID + col] = sc;
    shift[seg * HID + col] = beta[col] - mu * sc;
}

// ---------- in-place BN + fast GELU over Yb ----------
__global__ __launch_bounds__(256) void bngelu(unsigned short* __restrict__ Yb,
                                              const float* __restrict__ scale,
                                              const float* __restrict__ shift)
{
    size_t i = ((size_t)blockIdx.x * 256 + threadIdx.x) * 8;
    int row = (int)(i >> 10);
    int seg = (row < BATCH) ? 0 : (row < 2 * BATCH) ? 1 : 2;
    int col = (int)(i & 1023);
    float4 sc0 = *(const float4*)(scale + seg * HID + col);
    float4 sc1 = *(const float4*)(scale + seg * HID + col + 4);
    float4 sh0 = *(const float4*)(shift + seg * HID + col);
    float4 sh1 = *(const float4*)(shift + seg * HID + col + 4);
    float sc[8] = { sc0.x, sc0.y, sc0.z, sc0.w, sc1.x, sc1.y, sc1.z, sc1.w };
    float sh[8] = { sh0.x, sh0.y, sh0.z, sh0.w, sh1.x, sh1.y, sh1.z, sh1.w };
    uint4 v = *(uint4*)&Yb[i];
    unsigned short* u = (unsigned short*)&v;
    #pragma unroll
    for (int j = 0; j < 8; j++) {
        float f = fmaf(b2f(u[j]), sc[j], sh[j]);
        u[j] = f2b(gelu_fast(f));
    }
    *(uint4*)&Yb[i] = v;
}

// ---------- L2 normalize rows; read bf16 pre-norm, write bf16 all + fp32 first 8192 ----------
__global__ __launch_bounds__(256) void l2norm(const unsigned short* __restrict__ Zpre,
                                              unsigned short* __restrict__ Zb,
                                              float* __restrict__ Zfp)
{
    __shared__ float scratch[4];
    size_t r = blockIdx.x;
    float v = b2f(Zpre[r * PROJ + threadIdx.x]);
    float t = blockReduceSumF(v * v, scratch);
    float scale = 1.0f / fmaxf(sqrtf(t), 1e-12f);
    float o = v * scale;
    Zb[r * PROJ + threadIdx.x] = f2b(o);
    if (r < 2 * BATCH) Zfp[r * PROJ + threadIdx.x] = o;
}

// ---------- two-pass hist top-k loss ----------
__global__ __launch_bounds__(256) void topk_loss(
    const unsigned short* __restrict__ simb,   // [CHUNK x NNEG]
    const float* __restrict__ z1, const float* __restrict__ z2,
    int rowOffset, float* __restrict__ rowloss)
{
    __shared__ int   hcnt[4096];
    __shared__ int   segc[256];
    __shared__ int   sufc[256];
    __shared__ float fscratch[4];
    __shared__ int   iscratch[4];
    __shared__ int   sel_seg;
    __shared__ int   sh_bt, sh_run;

    const int tid = threadIdx.x;
    const int grow = rowOffset + blockIdx.x;
    const unsigned short* srow = simb + (size_t)blockIdx.x * NNEG;

    #pragma unroll
    for (int j = 0; j < 16; j++) hcnt[tid * 16 + j] = 0;

    float p = z1[(size_t)grow * PROJ + tid] * z2[(size_t)grow * PROJ + tid];
    float pos = blockReduceSumF(p, fscratch);
    __syncthreads();

    // ---- pass 1: count histogram ----
    for (int i = tid * 8; i < NNEG; i += 256 * 8) {
        uint4 v4 = *(const uint4*)(srow + i);
        const unsigned short* u = (const unsigned short*)&v4;
        #pragma unroll
        for (int j = 0; j < 8; j++) {
            float v = b2f(u[j]);
            int k = (int)fmaf(v, 2048.f, 2048.f);
            k = min(max(k, 0), 4095);
            atomicAdd(&hcnt[k], 1);
        }
    }
    __syncthreads();

    int c = 0;
    #pragma unroll
    for (int j = 0; j < 16; j++) c += hcnt[tid * 16 + j];
    segc[tid] = c;
    sufc[tid] = c;
    __syncthreads();
    for (int st = 1; st < 256; st <<= 1) {
        int aC = (tid + st < 256) ? sufc[tid + st] : 0;
        __syncthreads();
        sufc[tid] += aC;
        __syncthreads();
    }
    if (sufc[tid] >= TOPK && sufc[tid] - segc[tid] < TOPK) sel_seg = tid;
    __syncthreads();
    if (tid == 0) {
        int t = sel_seg;
        int running = sufc[t] - segc[t];
        int bt = t * 16;
        for (int j = 15; j >= 0; j--) {
            int b = t * 16 + j;
            int cb = hcnt[b];
            if (running + cb >= TOPK) { bt = b; break; }
            running += cb;
        }
        sh_bt = bt; sh_run = running;
    }
    __syncthreads();
    const int bt = sh_bt;
    const float m = INV_T;

    // ---- pass 2: exp only above/at threshold bucket ----
    float s_above = 0.f, s_eq = 0.f;
    int c_eq = 0;
    for (int i = tid * 8; i < NNEG; i += 256 * 8) {
        uint4 v4 = *(const uint4*)(srow + i);
        const unsigned short* u = (const unsigned short*)&v4;
        #pragma unroll
        for (int j = 0; j < 8; j++) {
            float v = b2f(u[j]);
            int k = (int)fmaf(v, 2048.f, 2048.f);
            k = min(max(k, 0), 4095);
            if (k >= bt) {
                float e = __expf(fmaf(v, INV_T, -m));
                if (k > bt) s_above += e;
                else { s_eq += e; c_eq++; }
            }
        }
    }
    s_above = blockReduceSumF(s_above, fscratch);
    __syncthreads();
    s_eq = blockReduceSumF(s_eq, fscratch);
    c_eq = blockReduceSumI(c_eq, iscratch);
    if (tid == 0) {
        int need = TOPK - sh_run;
        float avg = s_eq / (float)c_eq;
        float total = s_above + (float)need * avg + __expf(fmaf(pos, INV_T, -m));
        rowloss[grow] = m + logf(total) - pos * INV_T;
    }
}

__global__ __launch_bounds__(256) void loss_reduce(const float* __restrict__ rowloss,
                                                   float* __restrict__ out)
{
    __shared__ float scratch[4];
    float s = 0.f;
    for (int i = threadIdx.x; i < BATCH; i += 256) s += rowloss[i];
    s = blockReduceSumF(s, scratch);
    if (threadIdx.x == 0) out[0] = s / (float)BATCH;
}

// ---------- launcher ----------
extern "C" void kernel_launch(void* const* d_in, const int* in_sizes, int n_in,
                              void* d_out, int out_size, void* d_ws, size_t ws_size,
                              hipStream_t stream)
{
    const float* h1    = (const float*)d_in[0];
    const float* h2    = (const float*)d_in[1];
    const float* hneg  = (const float*)d_in[2];
    const float* W1    = (const float*)d_in[3];
    const float* b1    = (const float*)d_in[4];
    const float* gamma = (const float*)d_in[5];
    const float* beta  = (const float*)d_in[6];
    const float* W2    = (const float*)d_in[7];
    const float* b2    = (const float*)d_in[8];
    float* out = (float*)d_out;
    float* ws  = (float*)d_ws;

    // workspace layout (float offsets); total 51,652,608 f = 206.6 MB
    unsigned short* hneg_b = (unsigned short*)ws;                 // 32768x1024 bf16 = 16,777,216 f
    unsigned short* Yb   = (unsigned short*)(ws + 16777216);      // 40960x1024 bf16 = 20,971,520 f
    unsigned short* Zpre = (unsigned short*)(ws + 37748736);      // 40960x256 bf16  =  5,242,880 f
    unsigned short* Zb   = (unsigned short*)(ws + 42991616);      // 40960x256 bf16  =  5,242,880 f
    float*          Zfp  = ws + 48234496;                         // 8192x256 f32    =  2,097,152 f
    unsigned short* W1b  = (unsigned short*)(ws + 50331648);      // 1M bf16         =    524,288 f
    unsigned short* W2b  = (unsigned short*)(ws + 50855936);      // 256K bf16       =    131,072 f
    float* partial = ws + 50987008;                               // (32+32+256)*2048 = 655,360 f
    float* s_scale = ws + 51642368;                               // 3*1024
    float* s_shift = ws + 51645440;                               // 3*1024
    float* rowloss = ws + 51648512;                               // 4096
    unsigned short* simb = hneg_b;                                // overlay (dead after GEMM1-hneg)
    unsigned short* h12b = Zb;                                    // overlay Zb (dead until l2norm)

    // conversions: weights + h_neg + h1/h2 -> bf16
    conv_f2b<<<1024, 256, 0, stream>>>(W1, W1b, HID * HID);
    conv_f2b<<<256, 256, 0, stream>>>(W2, W2b, PROJ * HID);
    conv_f2b8<<<16384, 256, 0, stream>>>(hneg, hneg_b);
    conv_f2b8<<<2048, 256, 0, stream>>>(h1, h12b);
    conv_f2b8<<<2048, 256, 0, stream>>>(h2, h12b + (size_t)BATCH * HID);

    // GEMM1: Yb = X_b @ W1b^T + b1
    {
        dim3 g(HID / BN, 2 * BATCH / BM);
        mfma_gemm<<<g, 256, 0, stream>>>(h12b, W1b, b1, Yb, 2 * BATCH, HID, HID);
        dim3 gn(HID / BN, NNEG / BM);
        mfma_gemm<<<gn, 256, 0, stream>>>(hneg_b, W1b, b1, Yb + (size_t)2 * BATCH * HID,
                                          NNEG, HID, HID);
    }

    const int rows[3] = { BATCH, BATCH, NNEG };
    const int yoff[3] = { 0, BATCH, 2 * BATCH };
    const int poff[3] = { 0, 32, 64 };

    // BN stats: atomic-free partials + fused reduce/finalize
    for (int s = 0; s < 3; s++) {
        bn_stats_partial<<<rows[s] / BNS_ROWS, 256, 0, stream>>>(
            Yb + (size_t)yoff[s] * HID, partial + (size_t)poff[s] * 2048);
    }
    bn_reduce_finalize<<<dim3(HID / 256, 3), 256, 0, stream>>>(partial, gamma, beta, s_scale, s_shift);

    // in-place BN + fast GELU on Yb
    bngelu<<<ROWS_TOTAL * HID / 8 / 256, 256, 0, stream>>>(Yb, s_scale, s_shift);

    // GEMM2: Zpre = Yb @ W2b^T + b2
    for (int s = 0; s < 3; s++) {
        dim3 g(PROJ / BN, rows[s] / BM);
        mfma_gemm<<<g, 256, 0, stream>>>(Yb + (size_t)yoff[s] * HID, W2b, b2,
                                         Zpre + (size_t)yoff[s] * PROJ,
                                         rows[s], PROJ, HID);
    }
    // L2 normalize (writes Zb — h12b overlay is dead by now)
    l2norm<<<ROWS_TOTAL, 256, 0, stream>>>(Zpre, Zb, Zfp);

    // sim chunks (bf16 sim): sim = z1_chunk @ z_neg^T, then two-pass hist top-k loss
    const unsigned short* znegb = Zb + (size_t)(2 * BATCH) * PROJ;
    const float* z2v = Zfp + (size_t)BATCH * PROJ;
    for (int c = 0; c < BATCH / CHUNK; c++) {
        dim3 g(NNEG / BN, CHUNK / BM);
        mfma_gemm<<<g, 256, 0, stream>>>(Zb + (size_t)(c * CHUNK) * PROJ, znegb, nullptr,
                                         simb, CHUNK, NNEG, PROJ);
        topk_loss<<<CHUNK, 256, 0, stream>>>(simb, Zfp, z2v, c * CHUNK, rowloss);
    }
    loss_reduce<<<1, 256, 0, stream>>>(rowloss, out);
}